// Round 3
// baseline (2777.452 us; speedup 1.0000x reference)
//
#include <hip/hip_runtime.h>
#include <math.h>

#define NN 2048
#define TT 32
#define FIN 5
#define HH 64
#define G4 256     // 4*H
#define GATH 16
#define CAP 256    // max CSC edges/column: mean 102, sigma ~10 -> +15 sigma safe
#define CH 8       // phase-B time-chunk: ihB regs = LNB*CH = 16 floats

// ---------- helpers ----------
__device__ __forceinline__ float sigf(float x) {
    return 1.0f / (1.0f + __expf(-x));
}
__device__ __forceinline__ float tanh_fast(float x) {
    x = fminf(fmaxf(x, -15.0f), 15.0f);
    float t = __expf(2.0f * x);
    return (t - 1.0f) / (t + 1.0f);
}
__device__ __forceinline__ float dot4(float4 a, float4 b) {
    return a.x * b.x + a.y * b.y + a.z * b.z + a.w * b.w;
}
__device__ __forceinline__ float lrelu_exp(float x) {
    x = (x > 0.0f) ? x : 0.2f * x;
    return __expf(x);
}

// ---------- fused 2-layer LSTM ----------
// R10: revert to the proven R7 structure (256 threads, row-per-thread,
// g_lds gate exchange, combine on tid<128 = 2 of 4 waves, zero bank
// conflicts). Fix R7's one defect — phase B needed 32 f4 of weights/thread
// (128 VGPRs) vs the compiler's 116 choice -> in-loop global weight reloads
// every timestep. Fix: hoist the non-recurrent w_ih1·h0_t matvec out of the
// serial loop into 8-step chunked bursts (hist holds all h0_t after phase A).
// Burst and recurrence REUSE the same 16-f4 weight array -> peak live
// weights 64 VGPRs; __launch_bounds__(256,4) (2nd arg = blocks/CU on this
// toolchain, per R8/R9 evidence) caps at 128 VGPR = 4 waves/SIMD resident.
#define LNB 2
__global__ __launch_bounds__(256, 4)
void k_lstm(
    const float* __restrict__ inputs,
    const float* __restrict__ w_ih0, const float* __restrict__ w_hh0,
    const float* __restrict__ b_ih0, const float* __restrict__ b_hh0,
    const float* __restrict__ w_ih1, const float* __restrict__ w_hh1,
    const float* __restrict__ b_ih1, const float* __restrict__ b_hh1,
    float* __restrict__ x_out)
{
    __shared__ float x_lds[LNB * TT * FIN];        // 320 f
    __shared__ float hist[LNB][TT + 1][HH];        // 4224 f = 16.9 KB
    __shared__ float g_lds[LNB * G4];              // 512 f
    __shared__ float h1_lds[LNB * HH];             // 128 f

    const int tid = threadIdx.x;
    const int n0 = blockIdx.x * LNB;
    const int g = tid;                 // gate row 0..255
    const int cnb = tid >> 6;          // combine: node (tid<128): 0..1
    const int ck = tid & 63;           // combine: cell 0..63

    for (int idx = tid; idx < LNB * TT * FIN; idx += 256)
        x_lds[idx] = inputs[n0 * (TT * FIN) + idx];
    if (tid < LNB * HH) {
        hist[tid >> 6][0][tid & 63] = 0.0f;
        h1_lds[tid] = 0.0f;
    }

    // ================= Phase A: layer 0 (R7 verbatim) =================
    {
        float4 w0[16];
        {
            const float4* p = (const float4*)(w_hh0 + g * HH);
            #pragma unroll
            for (int k = 0; k < 16; ++k) w0[k] = p[k];
        }
        float xw0 = w_ih0[g * FIN + 0];
        float xw1 = w_ih0[g * FIN + 1];
        float xw2 = w_ih0[g * FIN + 2];
        float xw3 = w_ih0[g * FIN + 3];
        float xw4 = w_ih0[g * FIN + 4];
        const float bias0 = b_ih0[g] + b_hh0[g];
        float cA = 0.0f;

        __syncthreads();

        for (int t = 1; t <= TT; ++t) {
            #pragma unroll
            for (int nb = 0; nb < LNB; ++nb) {
                const float4* hv = (const float4*)&hist[nb][t - 1][0];
                float s0 = 0.f, s1 = 0.f, s2 = 0.f, s3 = 0.f;
                #pragma unroll
                for (int k = 0; k < 4; ++k) {
                    s0 += dot4(w0[k],      hv[k]);
                    s1 += dot4(w0[4 + k],  hv[4 + k]);
                    s2 += dot4(w0[8 + k],  hv[8 + k]);
                    s3 += dot4(w0[12 + k], hv[12 + k]);
                }
                const float* xv = &x_lds[nb * (TT * FIN) + (t - 1) * FIN];
                float a = bias0 + xw0 * xv[0] + xw1 * xv[1] + xw2 * xv[2] +
                          xw3 * xv[3] + xw4 * xv[4];
                g_lds[nb * G4 + g] = a + (s0 + s1) + (s2 + s3);
            }
            __syncthreads();
            if (tid < LNB * HH) {
                const int base = cnb * G4 + ck;
                float gi = g_lds[base];
                float gf = g_lds[base + 64];
                float gg = g_lds[base + 128];
                float go = g_lds[base + 192];
                cA = sigf(gf) * cA + sigf(gi) * tanh_fast(gg);
                hist[cnb][t][ck] = sigf(go) * tanh_fast(cA);
            }
            __syncthreads();
        }
    }

    // ================= Phase B: layer 1, chunked ih-burst =================
    {
        const float bias1 = b_ih1[g] + b_hh1[g];
        float cB = 0.0f;

        #pragma unroll 1
        for (int cch = 0; cch < TT / CH; ++cch) {
            float4 wv[16];                 // reused: w_ih1 then w_hh1
            {
                const float4* p = (const float4*)(w_ih1 + g * HH);
                #pragma unroll
                for (int k = 0; k < 16; ++k) wv[k] = p[k];
            }
            // ---- burst: ihB[nb][tt] = bias1 + w_ih1[g]·h0_t (no barriers,
            //      full ILP; hist is read-only here) ----
            float ihB[LNB][CH];
            #pragma unroll
            for (int tt = 0; tt < CH; ++tt) {
                const int t = cch * CH + tt + 1;
                #pragma unroll
                for (int nb = 0; nb < LNB; ++nb) {
                    const float4* hv = (const float4*)&hist[nb][t][0];
                    float s0 = 0.f, s1 = 0.f, s2 = 0.f, s3 = 0.f;
                    #pragma unroll
                    for (int k = 0; k < 4; ++k) {
                        s0 += dot4(wv[k],      hv[k]);
                        s1 += dot4(wv[4 + k],  hv[4 + k]);
                        s2 += dot4(wv[8 + k],  hv[8 + k]);
                        s3 += dot4(wv[12 + k], hv[12 + k]);
                    }
                    ihB[nb][tt] = bias1 + (s0 + s1) + (s2 + s3);
                }
            }
            asm volatile("" ::: "memory");  // keep wh loads out of the burst
            {
                const float4* p = (const float4*)(w_hh1 + g * HH);
                #pragma unroll
                for (int k = 0; k < 16; ++k) wv[k] = p[k];
            }
            // ---- recurrence: 8 steps, hh-matvec only ----
            #pragma unroll
            for (int tt = 0; tt < CH; ++tt) {
                #pragma unroll
                for (int nb = 0; nb < LNB; ++nb) {
                    const float4* hv = (const float4*)&h1_lds[nb * HH];
                    float s0 = 0.f, s1 = 0.f, s2 = 0.f, s3 = 0.f;
                    #pragma unroll
                    for (int k = 0; k < 4; ++k) {
                        s0 += dot4(wv[k],      hv[k]);
                        s1 += dot4(wv[4 + k],  hv[4 + k]);
                        s2 += dot4(wv[8 + k],  hv[8 + k]);
                        s3 += dot4(wv[12 + k], hv[12 + k]);
                    }
                    g_lds[nb * G4 + g] = ihB[nb][tt] + (s0 + s1) + (s2 + s3);
                }
                __syncthreads();
                if (tid < LNB * HH) {
                    const int base = cnb * G4 + ck;
                    float gi = g_lds[base];
                    float gf = g_lds[base + 64];
                    float gg = g_lds[base + 128];
                    float go = g_lds[base + 192];
                    cB = sigf(gf) * cB + sigf(gi) * tanh_fast(gg);
                    float hA = sigf(go) * tanh_fast(cB);
                    h1_lds[cnb * HH + ck] = hA;
                    if (cch == (TT / CH) - 1 && tt == CH - 1)
                        x_out[(n0 + cnb) * HH + ck] = hA;
                }
                __syncthreads();
            }
        }
    }
}

// ---------- zero the edge-build counters ----------
__global__ void k_zero(int* __restrict__ cnt, int* __restrict__ nfull)
{
    int i = blockIdx.x * 256 + threadIdx.x;
    if (i < NN) cnt[i] = 0;
    if (i == 0) *nfull = 0;
}

// ---------- build CSC edge list + row_full in one rel_mask scan ----------
__global__ __launch_bounds__(256) void k_edges(
    const float* __restrict__ rel_mask,
    int* __restrict__ cnt, int* __restrict__ csc,
    int* __restrict__ row_full, int* __restrict__ full_list,
    int* __restrict__ nfull)
{
    const int i = blockIdx.x;
    const int tid = threadIdx.x;
    __shared__ int s_any;
    if (tid == 0) s_any = 0;
    __syncthreads();
    bool mine = false;
    for (int j = tid; j < NN; j += 256) {
        float rm = rel_mask[i * NN + j];
        bool edge = (rm == 0.0f);
        mine |= edge;
        if (edge && j != i) {
            int slot = atomicAdd(&cnt[j], 1);
            if (slot < CAP) csc[j * CAP + slot] = i;
        }
    }
    if (mine) atomicOr(&s_any, 1);
    __syncthreads();
    if (tid == 0) {
        row_full[i] = s_any ? 0 : 1;
        if (!s_any) {
            int k = atomicAdd(nfull, 1);
            full_list[k] = i;
        }
    }
}

// ---------- h1 = x @ gat1_W ; es1/ed1 dots ----------
__global__ __launch_bounds__(256) void k_h1(
    const float* __restrict__ x, const float* __restrict__ W,
    const float* __restrict__ a_s, const float* __restrict__ a_d,
    float* __restrict__ h1g, float* __restrict__ es1, float* __restrict__ ed1)
{
    __shared__ float Wl[HH * GATH];
    __shared__ float xl[16 * 65];
    __shared__ float h1l[16 * GATH];
    const int tid = threadIdx.x;
    const int n0 = blockIdx.x * 16;
    for (int idx = tid; idx < HH * GATH; idx += 256) Wl[idx] = W[idx];
    for (int idx = tid; idx < 16 * HH; idx += 256) {
        int ln = idx >> 6, k = idx & 63;
        xl[ln * 65 + k] = x[(n0 + ln) * HH + k];
    }
    __syncthreads();
    const int ln = tid >> 4, jj = tid & 15;
    float acc = 0.0f;
    #pragma unroll 8
    for (int k = 0; k < HH; ++k) acc += xl[ln * 65 + k] * Wl[k * GATH + jj];
    h1g[(n0 + ln) * GATH + jj] = acc;
    h1l[ln * GATH + jj] = acc;
    __syncthreads();
    if (tid < 16) {
        float e_s = 0.0f, e_d = 0.0f;
        #pragma unroll
        for (int t = 0; t < GATH; ++t) {
            float hv = h1l[tid * GATH + t];
            e_s += hv * a_s[t];
            e_d += hv * a_d[t];
        }
        es1[n0 + tid] = e_s;
        ed1[n0 + tid] = e_d;
    }
}

// ---------- GAT1 sparse: 4 cols/block, 4 edge-groups x 16 dims ----------
__global__ __launch_bounds__(256) void k_gat1s(
    const int* __restrict__ cnt, const int* __restrict__ csc,
    const int* __restrict__ row_full, const int* __restrict__ full_list,
    const int* __restrict__ nfull,
    const float* __restrict__ h1g, const float* __restrict__ es1,
    const float* __restrict__ ed1, const float* __restrict__ gat1_b,
    float* __restrict__ hrel)
{
    const int tid = threadIdx.x;
    const int lc = tid >> 6;          // col in block 0..3
    const int grp = (tid >> 4) & 3;   // edge group 0..3
    const int d = tid & 15;           // h-dim 0..15
    const int j = blockIdx.x * 4 + lc;
    const float edj = ed1[j];
    float acc = 0.0f, l = 0.0f;

    const int n = min(cnt[j], CAP);
    const int* lst = csc + j * CAP;
    for (int e = grp; e < n; e += 4) {
        int i = lst[e];
        float p = lrelu_exp(es1[i] + edj);
        l += p;
        acc += p * h1g[i * GATH + d];
    }
    if (grp == 0 && !row_full[j]) {          // self edge (diag)
        float p = lrelu_exp(es1[j] + edj);
        l += p;
        acc += p * h1g[j * GATH + d];
    }
    const int nf = *nfull;                    // full rows adjacent everywhere
    for (int f = grp; f < nf; f += 4) {
        int i = full_list[f];
        float p = lrelu_exp(es1[i] + edj);
        l += p;
        acc += p * h1g[i * GATH + d];
    }

    __shared__ float sacc[4][4][GATH];
    __shared__ float sl[4][4];
    sacc[lc][grp][d] = acc;
    if (d == 0) sl[lc][grp] = l;
    __syncthreads();
    if (grp == 0) {
        float a = sacc[lc][0][d] + sacc[lc][1][d] + sacc[lc][2][d] + sacc[lc][3][d];
        float L = sl[lc][0] + sl[lc][1] + sl[lc][2] + sl[lc][3];
        hrel[j * GATH + d] = fmaxf(a / L + gat1_b[d], 0.0f);
    }
}

// ---------- h2 = hrel @ gat2_W ; es2/ed2 ----------
__global__ __launch_bounds__(256) void k_h2(
    const float* __restrict__ hrel, const float* __restrict__ W2,
    const float* __restrict__ a_s, const float* __restrict__ a_d,
    float* __restrict__ h2g, float* __restrict__ es2, float* __restrict__ ed2)
{
    __shared__ float Wl[GATH * HH];
    __shared__ float hl[4 * 17];
    __shared__ float h2l[4 * HH];
    const int tid = threadIdx.x;
    const int n0 = blockIdx.x * 4;
    for (int idx = tid; idx < GATH * HH; idx += 256) Wl[idx] = W2[idx];
    if (tid < 64) {
        int ln = tid >> 4, k = tid & 15;
        hl[ln * 17 + k] = hrel[(n0 + ln) * GATH + k];
    }
    __syncthreads();
    const int ln = tid >> 6, jj = tid & 63;
    float acc = 0.0f;
    #pragma unroll
    for (int k = 0; k < GATH; ++k) acc += hl[ln * 17 + k] * Wl[k * HH + jj];
    h2g[(n0 + ln) * HH + jj] = acc;
    h2l[ln * HH + jj] = acc;
    __syncthreads();
    if (tid < 4) {
        float e_s = 0.0f, e_d = 0.0f;
        #pragma unroll 16
        for (int t = 0; t < HH; ++t) {
            float hv = h2l[tid * HH + t];
            e_s += hv * a_s[t];
            e_d += hv * a_d[t];
        }
        es2[n0 + tid] = e_s;
        ed2[n0 + tid] = e_d;
    }
}

// ---------- GAT2 sparse + fc + leaky_relu: 1 col/block ----------
__global__ __launch_bounds__(256) void k_gat2s(
    const int* __restrict__ cnt, const int* __restrict__ csc,
    const int* __restrict__ row_full, const int* __restrict__ full_list,
    const int* __restrict__ nfull,
    const float* __restrict__ h2g, const float* __restrict__ es2,
    const float* __restrict__ ed2, const float* __restrict__ gat2_b,
    const float* __restrict__ fc_W, const float* __restrict__ fc_b,
    float* __restrict__ out)
{
    const int tid = threadIdx.x;
    const int grp = tid >> 6;         // edge group 0..3
    const int d = tid & 63;           // h-dim 0..63
    const int j = blockIdx.x;
    const float edj = ed2[j];
    float acc = 0.0f, l = 0.0f;

    const int n = min(cnt[j], CAP);
    const int* lst = csc + j * CAP;
    for (int e = grp; e < n; e += 4) {
        int i = lst[e];
        float p = lrelu_exp(es2[i] + edj);
        l += p;
        acc += p * h2g[i * HH + d];
    }
    if (grp == 0 && !row_full[j]) {
        float p = lrelu_exp(es2[j] + edj);
        l += p;
        acc += p * h2g[j * HH + d];
    }
    const int nf = *nfull;
    for (int f = grp; f < nf; f += 4) {
        int i = full_list[f];
        float p = lrelu_exp(es2[i] + edj);
        l += p;
        acc += p * h2g[i * HH + d];
    }

    __shared__ float sacc[4][HH];
    __shared__ float sl[4];
    sacc[grp][d] = acc;
    if (d == 0) sl[grp] = l;
    __syncthreads();
    if (grp == 0) {                    // tid 0..63 = one wave
        float a = sacc[0][d] + sacc[1][d] + sacc[2][d] + sacc[3][d];
        float L = sl[0] + sl[1] + sl[2] + sl[3];
        float v = a / L + gat2_b[d];
        float t = v * fc_W[d];
        #pragma unroll
        for (int off = 32; off >= 1; off >>= 1)
            t += __shfl_down(t, off, 64);
        if (d == 0) {
            float r = t + fc_b[0];
            out[j] = (r > 0.0f) ? r : 0.2f * r;
        }
    }
}

extern "C" void kernel_launch(void* const* d_in, const int* in_sizes, int n_in,
                              void* d_out, int out_size, void* d_ws, size_t ws_size,
                              hipStream_t stream)
{
    const float* inputs   = (const float*)d_in[0];
    // d_in[1] (relation), d_in[3] (rel_w_W), d_in[4] (rel_w_b) are dead:
    // softmax(rel_mask + weight) > 0 depends only on rel_mask.
    const float* rel_mask = (const float*)d_in[2];
    const float* w_ih0 = (const float*)d_in[5];
    const float* w_hh0 = (const float*)d_in[6];
    const float* b_ih0 = (const float*)d_in[7];
    const float* b_hh0 = (const float*)d_in[8];
    const float* w_ih1 = (const float*)d_in[9];
    const float* w_hh1 = (const float*)d_in[10];
    const float* b_ih1 = (const float*)d_in[11];
    const float* b_hh1 = (const float*)d_in[12];
    const float* gat1_W  = (const float*)d_in[13];
    const float* gat1_as = (const float*)d_in[14];
    const float* gat1_ad = (const float*)d_in[15];
    const float* gat1_b  = (const float*)d_in[16];
    const float* gat2_W  = (const float*)d_in[17];
    const float* gat2_as = (const float*)d_in[18];
    const float* gat2_ad = (const float*)d_in[19];
    const float* gat2_b  = (const float*)d_in[20];
    const float* fc_W = (const float*)d_in[21];
    const float* fc_b = (const float*)d_in[22];
    float* out = (float*)d_out;

    float* ws = (float*)d_ws;
    float* x_out = ws;                       // 2048*64
    float* h1g = x_out + NN * HH;            // 2048*16
    float* es1 = h1g + NN * GATH;            // 2048
    float* ed1 = es1 + NN;                   // 2048
    float* hrel = ed1 + NN;                  // 2048*16
    float* h2g = hrel + NN * GATH;           // 2048*64
    float* es2 = h2g + NN * HH;              // 2048
    float* ed2 = es2 + NN;                   // 2048
    int* cnt = (int*)(ed2 + NN);             // 2048
    int* row_full = cnt + NN;                // 2048
    int* full_list = row_full + NN;          // 2048
    int* nfull = full_list + NN;             // 1 (+pad)
    int* csc = nfull + 8;                    // 2048*CAP = 2 MB

    k_zero<<<(NN + 255) / 256, 256, 0, stream>>>(cnt, nfull);
    k_edges<<<NN, 256, 0, stream>>>(rel_mask, cnt, csc, row_full, full_list, nfull);
    k_lstm<<<NN / LNB, 256, 0, stream>>>(inputs, w_ih0, w_hh0, b_ih0, b_hh0,
                                         w_ih1, w_hh1, b_ih1, b_hh1, x_out);
    k_h1<<<NN / 16, 256, 0, stream>>>(x_out, gat1_W, gat1_as, gat1_ad, h1g, es1, ed1);
    k_gat1s<<<NN / 4, 256, 0, stream>>>(cnt, csc, row_full, full_list, nfull,
                                        h1g, es1, ed1, gat1_b, hrel);
    k_h2<<<NN / 4, 256, 0, stream>>>(hrel, gat2_W, gat2_as, gat2_ad, h2g, es2, ed2);
    k_gat2s<<<NN, 256, 0, stream>>>(cnt, csc, row_full, full_list, nfull,
                                    h2g, es2, ed2, gat2_b, fc_W, fc_b, out);
}

// Round 4
// 2177.680 us; speedup vs baseline: 1.2754x; 1.2754x over previous
//
#include <hip/hip_runtime.h>
#include <math.h>

#define NN 2048
#define TT 32
#define FIN 5
#define HH 64
#define G4 256     // 4*H
#define GATH 16
#define CAP 256    // max CSC edges/column: mean 102, sigma ~10 -> +15 sigma safe
#define CH 8       // phase-B time-chunk: ihB regs = LNB*CH = 16 floats

// ---------- helpers ----------
__device__ __forceinline__ float sigf(float x) {
    return 1.0f / (1.0f + __expf(-x));
}
__device__ __forceinline__ float tanh_fast(float x) {
    x = fminf(fmaxf(x, -15.0f), 15.0f);
    float t = __expf(2.0f * x);
    return (t - 1.0f) / (t + 1.0f);
}
__device__ __forceinline__ float dot4(float4 a, float4 b) {
    return a.x * b.x + a.y * b.y + a.z * b.z + a.w * b.w;
}
__device__ __forceinline__ float lrelu_exp(float x) {
    x = (x > 0.0f) ? x : 0.2f * x;
    return __expf(x);
}

// ---------- fused 2-layer LSTM ----------
// R11 = R10 structure with the launch-bounds cap fixed.
// Empirical rule for THIS toolchain (R7/R8/R9/R10 measurements):
//   __launch_bounds__ 2nd arg -> VGPR cap ~= 256/arg, independent of block
//   size:  (256,1)->116ok  (512,2)->108ok  (256,4)->64 SPILL  (512,4)->64 SPILL.
// So arg=2 gives the 128-reg cap this kernel needs (~116 live).
// Structure (R10): R7's 256-thread row-per-thread mapping + g_lds gate
// exchange (zero bank conflicts), with phase B's non-recurrent w_ih1*h0_t
// matvec hoisted into 8-step barrier-free bursts; burst and recurrence
// REUSE one 16-f4 weight array so peak live weights = 64 VGPRs.
#define LNB 2
__global__ __launch_bounds__(256, 2)
void k_lstm(
    const float* __restrict__ inputs,
    const float* __restrict__ w_ih0, const float* __restrict__ w_hh0,
    const float* __restrict__ b_ih0, const float* __restrict__ b_hh0,
    const float* __restrict__ w_ih1, const float* __restrict__ w_hh1,
    const float* __restrict__ b_ih1, const float* __restrict__ b_hh1,
    float* __restrict__ x_out)
{
    __shared__ float x_lds[LNB * TT * FIN];        // 320 f
    __shared__ float hist[LNB][TT + 1][HH];        // 4224 f = 16.9 KB
    __shared__ float g_lds[LNB * G4];              // 512 f
    __shared__ float h1_lds[LNB * HH];             // 128 f

    const int tid = threadIdx.x;
    const int n0 = blockIdx.x * LNB;
    const int g = tid;                 // gate row 0..255
    const int cnb = tid >> 6;          // combine: node (tid<128): 0..1
    const int ck = tid & 63;           // combine: cell 0..63

    for (int idx = tid; idx < LNB * TT * FIN; idx += 256)
        x_lds[idx] = inputs[n0 * (TT * FIN) + idx];
    if (tid < LNB * HH) {
        hist[tid >> 6][0][tid & 63] = 0.0f;
        h1_lds[tid] = 0.0f;
    }

    // ================= Phase A: layer 0 (R7 verbatim) =================
    {
        float4 w0[16];
        {
            const float4* p = (const float4*)(w_hh0 + g * HH);
            #pragma unroll
            for (int k = 0; k < 16; ++k) w0[k] = p[k];
        }
        float xw0 = w_ih0[g * FIN + 0];
        float xw1 = w_ih0[g * FIN + 1];
        float xw2 = w_ih0[g * FIN + 2];
        float xw3 = w_ih0[g * FIN + 3];
        float xw4 = w_ih0[g * FIN + 4];
        const float bias0 = b_ih0[g] + b_hh0[g];
        float cA = 0.0f;

        __syncthreads();

        for (int t = 1; t <= TT; ++t) {
            #pragma unroll
            for (int nb = 0; nb < LNB; ++nb) {
                const float4* hv = (const float4*)&hist[nb][t - 1][0];
                float s0 = 0.f, s1 = 0.f, s2 = 0.f, s3 = 0.f;
                #pragma unroll
                for (int k = 0; k < 4; ++k) {
                    s0 += dot4(w0[k],      hv[k]);
                    s1 += dot4(w0[4 + k],  hv[4 + k]);
                    s2 += dot4(w0[8 + k],  hv[8 + k]);
                    s3 += dot4(w0[12 + k], hv[12 + k]);
                }
                const float* xv = &x_lds[nb * (TT * FIN) + (t - 1) * FIN];
                float a = bias0 + xw0 * xv[0] + xw1 * xv[1] + xw2 * xv[2] +
                          xw3 * xv[3] + xw4 * xv[4];
                g_lds[nb * G4 + g] = a + (s0 + s1) + (s2 + s3);
            }
            __syncthreads();
            if (tid < LNB * HH) {
                const int base = cnb * G4 + ck;
                float gi = g_lds[base];
                float gf = g_lds[base + 64];
                float gg = g_lds[base + 128];
                float go = g_lds[base + 192];
                cA = sigf(gf) * cA + sigf(gi) * tanh_fast(gg);
                hist[cnb][t][ck] = sigf(go) * tanh_fast(cA);
            }
            __syncthreads();
        }
    }

    // ================= Phase B: layer 1, chunked ih-burst =================
    {
        const float bias1 = b_ih1[g] + b_hh1[g];
        float cB = 0.0f;

        #pragma unroll 1
        for (int cch = 0; cch < TT / CH; ++cch) {
            float4 wv[16];                 // reused: w_ih1 then w_hh1
            {
                const float4* p = (const float4*)(w_ih1 + g * HH);
                #pragma unroll
                for (int k = 0; k < 16; ++k) wv[k] = p[k];
            }
            // ---- burst: ihB[nb][tt] = bias1 + w_ih1[g]·h0_t (no barriers,
            //      full ILP; hist is read-only here) ----
            float ihB[LNB][CH];
            #pragma unroll
            for (int tt = 0; tt < CH; ++tt) {
                const int t = cch * CH + tt + 1;
                #pragma unroll
                for (int nb = 0; nb < LNB; ++nb) {
                    const float4* hv = (const float4*)&hist[nb][t][0];
                    float s0 = 0.f, s1 = 0.f, s2 = 0.f, s3 = 0.f;
                    #pragma unroll
                    for (int k = 0; k < 4; ++k) {
                        s0 += dot4(wv[k],      hv[k]);
                        s1 += dot4(wv[4 + k],  hv[4 + k]);
                        s2 += dot4(wv[8 + k],  hv[8 + k]);
                        s3 += dot4(wv[12 + k], hv[12 + k]);
                    }
                    ihB[nb][tt] = bias1 + (s0 + s1) + (s2 + s3);
                }
            }
            asm volatile("" ::: "memory");  // keep wh loads out of the burst
            {
                const float4* p = (const float4*)(w_hh1 + g * HH);
                #pragma unroll
                for (int k = 0; k < 16; ++k) wv[k] = p[k];
            }
            // ---- recurrence: 8 steps, hh-matvec only ----
            #pragma unroll
            for (int tt = 0; tt < CH; ++tt) {
                #pragma unroll
                for (int nb = 0; nb < LNB; ++nb) {
                    const float4* hv = (const float4*)&h1_lds[nb * HH];
                    float s0 = 0.f, s1 = 0.f, s2 = 0.f, s3 = 0.f;
                    #pragma unroll
                    for (int k = 0; k < 4; ++k) {
                        s0 += dot4(wv[k],      hv[k]);
                        s1 += dot4(wv[4 + k],  hv[4 + k]);
                        s2 += dot4(wv[8 + k],  hv[8 + k]);
                        s3 += dot4(wv[12 + k], hv[12 + k]);
                    }
                    g_lds[nb * G4 + g] = ihB[nb][tt] + (s0 + s1) + (s2 + s3);
                }
                __syncthreads();
                if (tid < LNB * HH) {
                    const int base = cnb * G4 + ck;
                    float gi = g_lds[base];
                    float gf = g_lds[base + 64];
                    float gg = g_lds[base + 128];
                    float go = g_lds[base + 192];
                    cB = sigf(gf) * cB + sigf(gi) * tanh_fast(gg);
                    float hA = sigf(go) * tanh_fast(cB);
                    h1_lds[cnb * HH + ck] = hA;
                    if (cch == (TT / CH) - 1 && tt == CH - 1)
                        x_out[(n0 + cnb) * HH + ck] = hA;
                }
                __syncthreads();
            }
        }
    }
}

// ---------- zero the edge-build counters ----------
__global__ void k_zero(int* __restrict__ cnt, int* __restrict__ nfull)
{
    int i = blockIdx.x * 256 + threadIdx.x;
    if (i < NN) cnt[i] = 0;
    if (i == 0) *nfull = 0;
}

// ---------- build CSC edge list + row_full in one rel_mask scan ----------
__global__ __launch_bounds__(256) void k_edges(
    const float* __restrict__ rel_mask,
    int* __restrict__ cnt, int* __restrict__ csc,
    int* __restrict__ row_full, int* __restrict__ full_list,
    int* __restrict__ nfull)
{
    const int i = blockIdx.x;
    const int tid = threadIdx.x;
    __shared__ int s_any;
    if (tid == 0) s_any = 0;
    __syncthreads();
    bool mine = false;
    for (int j = tid; j < NN; j += 256) {
        float rm = rel_mask[i * NN + j];
        bool edge = (rm == 0.0f);
        mine |= edge;
        if (edge && j != i) {
            int slot = atomicAdd(&cnt[j], 1);
            if (slot < CAP) csc[j * CAP + slot] = i;
        }
    }
    if (mine) atomicOr(&s_any, 1);
    __syncthreads();
    if (tid == 0) {
        row_full[i] = s_any ? 0 : 1;
        if (!s_any) {
            int k = atomicAdd(nfull, 1);
            full_list[k] = i;
        }
    }
}

// ---------- h1 = x @ gat1_W ; es1/ed1 dots ----------
__global__ __launch_bounds__(256) void k_h1(
    const float* __restrict__ x, const float* __restrict__ W,
    const float* __restrict__ a_s, const float* __restrict__ a_d,
    float* __restrict__ h1g, float* __restrict__ es1, float* __restrict__ ed1)
{
    __shared__ float Wl[HH * GATH];
    __shared__ float xl[16 * 65];
    __shared__ float h1l[16 * GATH];
    const int tid = threadIdx.x;
    const int n0 = blockIdx.x * 16;
    for (int idx = tid; idx < HH * GATH; idx += 256) Wl[idx] = W[idx];
    for (int idx = tid; idx < 16 * HH; idx += 256) {
        int ln = idx >> 6, k = idx & 63;
        xl[ln * 65 + k] = x[(n0 + ln) * HH + k];
    }
    __syncthreads();
    const int ln = tid >> 4, jj = tid & 15;
    float acc = 0.0f;
    #pragma unroll 8
    for (int k = 0; k < HH; ++k) acc += xl[ln * 65 + k] * Wl[k * GATH + jj];
    h1g[(n0 + ln) * GATH + jj] = acc;
    h1l[ln * GATH + jj] = acc;
    __syncthreads();
    if (tid < 16) {
        float e_s = 0.0f, e_d = 0.0f;
        #pragma unroll
        for (int t = 0; t < GATH; ++t) {
            float hv = h1l[tid * GATH + t];
            e_s += hv * a_s[t];
            e_d += hv * a_d[t];
        }
        es1[n0 + tid] = e_s;
        ed1[n0 + tid] = e_d;
    }
}

// ---------- GAT1 sparse: 4 cols/block, 4 edge-groups x 16 dims ----------
__global__ __launch_bounds__(256) void k_gat1s(
    const int* __restrict__ cnt, const int* __restrict__ csc,
    const int* __restrict__ row_full, const int* __restrict__ full_list,
    const int* __restrict__ nfull,
    const float* __restrict__ h1g, const float* __restrict__ es1,
    const float* __restrict__ ed1, const float* __restrict__ gat1_b,
    float* __restrict__ hrel)
{
    const int tid = threadIdx.x;
    const int lc = tid >> 6;          // col in block 0..3
    const int grp = (tid >> 4) & 3;   // edge group 0..3
    const int d = tid & 15;           // h-dim 0..15
    const int j = blockIdx.x * 4 + lc;
    const float edj = ed1[j];
    float acc = 0.0f, l = 0.0f;

    const int n = min(cnt[j], CAP);
    const int* lst = csc + j * CAP;
    for (int e = grp; e < n; e += 4) {
        int i = lst[e];
        float p = lrelu_exp(es1[i] + edj);
        l += p;
        acc += p * h1g[i * GATH + d];
    }
    if (grp == 0 && !row_full[j]) {          // self edge (diag)
        float p = lrelu_exp(es1[j] + edj);
        l += p;
        acc += p * h1g[j * GATH + d];
    }
    const int nf = *nfull;                    // full rows adjacent everywhere
    for (int f = grp; f < nf; f += 4) {
        int i = full_list[f];
        float p = lrelu_exp(es1[i] + edj);
        l += p;
        acc += p * h1g[i * GATH + d];
    }

    __shared__ float sacc[4][4][GATH];
    __shared__ float sl[4][4];
    sacc[lc][grp][d] = acc;
    if (d == 0) sl[lc][grp] = l;
    __syncthreads();
    if (grp == 0) {
        float a = sacc[lc][0][d] + sacc[lc][1][d] + sacc[lc][2][d] + sacc[lc][3][d];
        float L = sl[lc][0] + sl[lc][1] + sl[lc][2] + sl[lc][3];
        hrel[j * GATH + d] = fmaxf(a / L + gat1_b[d], 0.0f);
    }
}

// ---------- h2 = hrel @ gat2_W ; es2/ed2 ----------
__global__ __launch_bounds__(256) void k_h2(
    const float* __restrict__ hrel, const float* __restrict__ W2,
    const float* __restrict__ a_s, const float* __restrict__ a_d,
    float* __restrict__ h2g, float* __restrict__ es2, float* __restrict__ ed2)
{
    __shared__ float Wl[GATH * HH];
    __shared__ float hl[4 * 17];
    __shared__ float h2l[4 * HH];
    const int tid = threadIdx.x;
    const int n0 = blockIdx.x * 4;
    for (int idx = tid; idx < GATH * HH; idx += 256) Wl[idx] = W2[idx];
    if (tid < 64) {
        int ln = tid >> 4, k = tid & 15;
        hl[ln * 17 + k] = hrel[(n0 + ln) * GATH + k];
    }
    __syncthreads();
    const int ln = tid >> 6, jj = tid & 63;
    float acc = 0.0f;
    #pragma unroll
    for (int k = 0; k < GATH; ++k) acc += hl[ln * 17 + k] * Wl[k * HH + jj];
    h2g[(n0 + ln) * HH + jj] = acc;
    h2l[ln * HH + jj] = acc;
    __syncthreads();
    if (tid < 4) {
        float e_s = 0.0f, e_d = 0.0f;
        #pragma unroll 16
        for (int t = 0; t < HH; ++t) {
            float hv = h2l[tid * HH + t];
            e_s += hv * a_s[t];
            e_d += hv * a_d[t];
        }
        es2[n0 + tid] = e_s;
        ed2[n0 + tid] = e_d;
    }
}

// ---------- GAT2 sparse + fc + leaky_relu: 1 col/block ----------
__global__ __launch_bounds__(256) void k_gat2s(
    const int* __restrict__ cnt, const int* __restrict__ csc,
    const int* __restrict__ row_full, const int* __restrict__ full_list,
    const int* __restrict__ nfull,
    const float* __restrict__ h2g, const float* __restrict__ es2,
    const float* __restrict__ ed2, const float* __restrict__ gat2_b,
    const float* __restrict__ fc_W, const float* __restrict__ fc_b,
    float* __restrict__ out)
{
    const int tid = threadIdx.x;
    const int grp = tid >> 6;         // edge group 0..3
    const int d = tid & 63;           // h-dim 0..63
    const int j = blockIdx.x;
    const float edj = ed2[j];
    float acc = 0.0f, l = 0.0f;

    const int n = min(cnt[j], CAP);
    const int* lst = csc + j * CAP;
    for (int e = grp; e < n; e += 4) {
        int i = lst[e];
        float p = lrelu_exp(es2[i] + edj);
        l += p;
        acc += p * h2g[i * HH + d];
    }
    if (grp == 0 && !row_full[j]) {
        float p = lrelu_exp(es2[j] + edj);
        l += p;
        acc += p * h2g[j * HH + d];
    }
    const int nf = *nfull;
    for (int f = grp; f < nf; f += 4) {
        int i = full_list[f];
        float p = lrelu_exp(es2[i] + edj);
        l += p;
        acc += p * h2g[i * HH + d];
    }

    __shared__ float sacc[4][HH];
    __shared__ float sl[4];
    sacc[grp][d] = acc;
    if (d == 0) sl[grp] = l;
    __syncthreads();
    if (grp == 0) {                    // tid 0..63 = one wave
        float a = sacc[0][d] + sacc[1][d] + sacc[2][d] + sacc[3][d];
        float L = sl[0] + sl[1] + sl[2] + sl[3];
        float v = a / L + gat2_b[d];
        float t = v * fc_W[d];
        #pragma unroll
        for (int off = 32; off >= 1; off >>= 1)
            t += __shfl_down(t, off, 64);
        if (d == 0) {
            float r = t + fc_b[0];
            out[j] = (r > 0.0f) ? r : 0.2f * r;
        }
    }
}

extern "C" void kernel_launch(void* const* d_in, const int* in_sizes, int n_in,
                              void* d_out, int out_size, void* d_ws, size_t ws_size,
                              hipStream_t stream)
{
    const float* inputs   = (const float*)d_in[0];
    // d_in[1] (relation), d_in[3] (rel_w_W), d_in[4] (rel_w_b) are dead:
    // softmax(rel_mask + weight) > 0 depends only on rel_mask.
    const float* rel_mask = (const float*)d_in[2];
    const float* w_ih0 = (const float*)d_in[5];
    const float* w_hh0 = (const float*)d_in[6];
    const float* b_ih0 = (const float*)d_in[7];
    const float* b_hh0 = (const float*)d_in[8];
    const float* w_ih1 = (const float*)d_in[9];
    const float* w_hh1 = (const float*)d_in[10];
    const float* b_ih1 = (const float*)d_in[11];
    const float* b_hh1 = (const float*)d_in[12];
    const float* gat1_W  = (const float*)d_in[13];
    const float* gat1_as = (const float*)d_in[14];
    const float* gat1_ad = (const float*)d_in[15];
    const float* gat1_b  = (const float*)d_in[16];
    const float* gat2_W  = (const float*)d_in[17];
    const float* gat2_as = (const float*)d_in[18];
    const float* gat2_ad = (const float*)d_in[19];
    const float* gat2_b  = (const float*)d_in[20];
    const float* fc_W = (const float*)d_in[21];
    const float* fc_b = (const float*)d_in[22];
    float* out = (float*)d_out;

    float* ws = (float*)d_ws;
    float* x_out = ws;                       // 2048*64
    float* h1g = x_out + NN * HH;            // 2048*16
    float* es1 = h1g + NN * GATH;            // 2048
    float* ed1 = es1 + NN;                   // 2048
    float* hrel = ed1 + NN;                  // 2048*16
    float* h2g = hrel + NN * GATH;           // 2048*64
    float* es2 = h2g + NN * HH;              // 2048
    float* ed2 = es2 + NN;                   // 2048
    int* cnt = (int*)(ed2 + NN);             // 2048
    int* row_full = cnt + NN;                // 2048
    int* full_list = row_full + NN;          // 2048
    int* nfull = full_list + NN;             // 1 (+pad)
    int* csc = nfull + 8;                    // 2048*CAP = 2 MB

    k_zero<<<(NN + 255) / 256, 256, 0, stream>>>(cnt, nfull);
    k_edges<<<NN, 256, 0, stream>>>(rel_mask, cnt, csc, row_full, full_list, nfull);
    k_lstm<<<NN / LNB, 256, 0, stream>>>(inputs, w_ih0, w_hh0, b_ih0, b_hh0,
                                         w_ih1, w_hh1, b_ih1, b_hh1, x_out);
    k_h1<<<NN / 16, 256, 0, stream>>>(x_out, gat1_W, gat1_as, gat1_ad, h1g, es1, ed1);
    k_gat1s<<<NN / 4, 256, 0, stream>>>(cnt, csc, row_full, full_list, nfull,
                                        h1g, es1, ed1, gat1_b, hrel);
    k_h2<<<NN / 4, 256, 0, stream>>>(hrel, gat2_W, gat2_as, gat2_ad, h2g, es2, ed2);
    k_gat2s<<<NN, 256, 0, stream>>>(cnt, csc, row_full, full_list, nfull,
                                    h2g, es2, ed2, gat2_b, fc_W, fc_b, out);
}

// Round 5
// 599.436 us; speedup vs baseline: 4.6334x; 3.6329x over previous
//
#include <hip/hip_runtime.h>
#include <math.h>

#define NN 2048
#define TT 32
#define FIN 5
#define HH 64
#define G4 256     // 4*H
#define GATH 16
#define CAP 256    // max CSC edges/column: mean 102, sigma ~10 -> +15 sigma safe

// ---------- helpers ----------
__device__ __forceinline__ float sigf(float x) {
    return 1.0f / (1.0f + __expf(-x));
}
__device__ __forceinline__ float tanh_fast(float x) {
    x = fminf(fmaxf(x, -15.0f), 15.0f);
    float t = __expf(2.0f * x);
    return (t - 1.0f) / (t + 1.0f);
}
__device__ __forceinline__ float dot4(float4 a, float4 b) {
    return a.x * b.x + a.y * b.y + a.z * b.z + a.w * b.w;
}
__device__ __forceinline__ float lrelu_exp(float x) {
    x = (x > 0.0f) ? x : 0.2f * x;
    return __expf(x);
}

// ---------- zero the edge-build counters ----------
__global__ void k_zero(int* __restrict__ cnt, int* __restrict__ nfull)
{
    int i = blockIdx.x * 256 + threadIdx.x;
    if (i < NN) cnt[i] = 0;
    if (i == 0) *nfull = 0;
}

// ---------- fused: 2-layer LSTM (even blocks) + edge build (odd blocks) ----
// R12: k_lstm reverted to the proven R7 body VERBATIM (202.7 us measured;
// R8-R11 restructures all lost to it — see journal). k_edges is folded in as
// the odd blocks of the same launch: edges is memory/atomic-bound and
// independent of the LSTM, so it executes in the LSTM's idle memory slots
// (lstm: VALUBusy 69%, hbm ~0.1%) instead of serializing as its own launch.
// Branch is block-uniform; LSTM path codegen identical to standalone R7.
#define LNB 2
__global__ __launch_bounds__(256, 1)
void k_lstm_edges(
    const float* __restrict__ inputs,
    const float* __restrict__ w_ih0, const float* __restrict__ w_hh0,
    const float* __restrict__ b_ih0, const float* __restrict__ b_hh0,
    const float* __restrict__ w_ih1, const float* __restrict__ w_hh1,
    const float* __restrict__ b_ih1, const float* __restrict__ b_hh1,
    float* __restrict__ x_out,
    const float* __restrict__ rel_mask,
    int* __restrict__ cnt, int* __restrict__ csc,
    int* __restrict__ row_full, int* __restrict__ full_list,
    int* __restrict__ nfull)
{
    const int tid = threadIdx.x;

    if (blockIdx.x & 1) {
        // ================= edge path: rows 2*(bid>>1), +1 =================
        __shared__ int s_any[2];
        const int r0 = (blockIdx.x >> 1) * 2;
        if (tid < 2) s_any[tid] = 0;
        __syncthreads();
        #pragma unroll
        for (int rr = 0; rr < 2; ++rr) {
            const int i = r0 + rr;
            bool mine = false;
            for (int j = tid; j < NN; j += 256) {
                float rm = rel_mask[i * NN + j];
                bool edge = (rm == 0.0f);
                mine |= edge;
                if (edge && j != i) {
                    int slot = atomicAdd(&cnt[j], 1);
                    if (slot < CAP) csc[j * CAP + slot] = i;
                }
            }
            if (mine) atomicOr(&s_any[rr], 1);
        }
        __syncthreads();
        if (tid < 2) {
            const int i = r0 + tid;
            int any = s_any[tid];
            row_full[i] = any ? 0 : 1;
            if (!any) {
                int k = atomicAdd(nfull, 1);
                full_list[k] = i;
            }
        }
        return;
    }

    // ================= LSTM path (R7 verbatim) =================
    __shared__ float x_lds[LNB * TT * FIN];        // 320 f
    __shared__ float hist[LNB][TT + 1][HH];        // 4224 f = 16.9 KB
    __shared__ float g_lds[LNB * G4];              // 512 f
    __shared__ float h1_lds[LNB * HH];             // 128 f

    const int n0 = (blockIdx.x >> 1) * LNB;
    const int g = tid;                 // gate row 0..255
    const int cnb = tid >> 6;          // combine: node (tid<128): 0..1
    const int ck = tid & 63;           // combine: cell 0..63

    for (int idx = tid; idx < LNB * TT * FIN; idx += 256)
        x_lds[idx] = inputs[n0 * (TT * FIN) + idx];
    if (tid < LNB * HH) {
        hist[tid >> 6][0][tid & 63] = 0.0f;
        h1_lds[tid] = 0.0f;
    }

    // ================= Phase A: layer 0 =================
    {
        float4 w0[16];
        {
            const float4* p = (const float4*)(w_hh0 + g * HH);
            #pragma unroll
            for (int k = 0; k < 16; ++k) w0[k] = p[k];
        }
        float xw0 = w_ih0[g * FIN + 0];
        float xw1 = w_ih0[g * FIN + 1];
        float xw2 = w_ih0[g * FIN + 2];
        float xw3 = w_ih0[g * FIN + 3];
        float xw4 = w_ih0[g * FIN + 4];
        const float bias0 = b_ih0[g] + b_hh0[g];
        float cA = 0.0f;

        __syncthreads();

        for (int t = 1; t <= TT; ++t) {
            #pragma unroll
            for (int nb = 0; nb < LNB; ++nb) {
                const float4* hv = (const float4*)&hist[nb][t - 1][0];
                float s0 = 0.f, s1 = 0.f, s2 = 0.f, s3 = 0.f;
                #pragma unroll
                for (int k = 0; k < 4; ++k) {
                    s0 += dot4(w0[k],      hv[k]);
                    s1 += dot4(w0[4 + k],  hv[4 + k]);
                    s2 += dot4(w0[8 + k],  hv[8 + k]);
                    s3 += dot4(w0[12 + k], hv[12 + k]);
                }
                const float* xv = &x_lds[nb * (TT * FIN) + (t - 1) * FIN];
                float a = bias0 + xw0 * xv[0] + xw1 * xv[1] + xw2 * xv[2] +
                          xw3 * xv[3] + xw4 * xv[4];
                g_lds[nb * G4 + g] = a + (s0 + s1) + (s2 + s3);
            }
            __syncthreads();
            if (tid < LNB * HH) {
                const int base = cnb * G4 + ck;
                float gi = g_lds[base];
                float gf = g_lds[base + 64];
                float gg = g_lds[base + 128];
                float go = g_lds[base + 192];
                cA = sigf(gf) * cA + sigf(gi) * tanh_fast(gg);
                hist[cnb][t][ck] = sigf(go) * tanh_fast(cA);
            }
            __syncthreads();
        }
    }

    // ================= Phase B: layer 1 =================
    {
        float4 wi[16], wh[16];
        {
            const float4* pi = (const float4*)(w_ih1 + g * HH);
            const float4* ph = (const float4*)(w_hh1 + g * HH);
            #pragma unroll
            for (int k = 0; k < 16; ++k) { wi[k] = pi[k]; wh[k] = ph[k]; }
        }
        const float bias1 = b_ih1[g] + b_hh1[g];
        float cA = 0.0f;

        for (int t = 1; t <= TT; ++t) {
            #pragma unroll
            for (int nb = 0; nb < LNB; ++nb) {
                const float4* xv = (const float4*)&hist[nb][t][0];
                const float4* hv = (const float4*)&h1_lds[nb * HH];
                float s0 = 0.f, s1 = 0.f, s2 = 0.f, s3 = 0.f;
                float u0 = 0.f, u1 = 0.f, u2 = 0.f, u3 = 0.f;
                #pragma unroll
                for (int k = 0; k < 4; ++k) {
                    s0 += dot4(wi[k],      xv[k]);
                    s1 += dot4(wi[4 + k],  xv[4 + k]);
                    s2 += dot4(wi[8 + k],  xv[8 + k]);
                    s3 += dot4(wi[12 + k], xv[12 + k]);
                    u0 += dot4(wh[k],      hv[k]);
                    u1 += dot4(wh[4 + k],  hv[4 + k]);
                    u2 += dot4(wh[8 + k],  hv[8 + k]);
                    u3 += dot4(wh[12 + k], hv[12 + k]);
                }
                g_lds[nb * G4 + g] =
                    bias1 + ((s0 + s1) + (s2 + s3)) + ((u0 + u1) + (u2 + u3));
            }
            __syncthreads();
            if (tid < LNB * HH) {
                const int base = cnb * G4 + ck;
                float gi = g_lds[base];
                float gf = g_lds[base + 64];
                float gg = g_lds[base + 128];
                float go = g_lds[base + 192];
                cA = sigf(gf) * cA + sigf(gi) * tanh_fast(gg);
                float hA = sigf(go) * tanh_fast(cA);
                h1_lds[cnb * HH + ck] = hA;
                if (t == TT) x_out[(n0 + cnb) * HH + ck] = hA;
            }
            __syncthreads();
        }
    }
}

// ---------- h1 = x @ gat1_W ; es1/ed1 dots ----------
__global__ __launch_bounds__(256) void k_h1(
    const float* __restrict__ x, const float* __restrict__ W,
    const float* __restrict__ a_s, const float* __restrict__ a_d,
    float* __restrict__ h1g, float* __restrict__ es1, float* __restrict__ ed1)
{
    __shared__ float Wl[HH * GATH];
    __shared__ float xl[16 * 65];
    __shared__ float h1l[16 * GATH];
    const int tid = threadIdx.x;
    const int n0 = blockIdx.x * 16;
    for (int idx = tid; idx < HH * GATH; idx += 256) Wl[idx] = W[idx];
    for (int idx = tid; idx < 16 * HH; idx += 256) {
        int ln = idx >> 6, k = idx & 63;
        xl[ln * 65 + k] = x[(n0 + ln) * HH + k];
    }
    __syncthreads();
    const int ln = tid >> 4, jj = tid & 15;
    float acc = 0.0f;
    #pragma unroll 8
    for (int k = 0; k < HH; ++k) acc += xl[ln * 65 + k] * Wl[k * GATH + jj];
    h1g[(n0 + ln) * GATH + jj] = acc;
    h1l[ln * GATH + jj] = acc;
    __syncthreads();
    if (tid < 16) {
        float e_s = 0.0f, e_d = 0.0f;
        #pragma unroll
        for (int t = 0; t < GATH; ++t) {
            float hv = h1l[tid * GATH + t];
            e_s += hv * a_s[t];
            e_d += hv * a_d[t];
        }
        es1[n0 + tid] = e_s;
        ed1[n0 + tid] = e_d;
    }
}

// ---------- fused GAT1 sparse + h2 = relu(hrel) @ gat2_W + es2/ed2 --------
// R12: k_h2 folded into the gat1s epilogue. hrel fed ONLY k_h2, so it never
// touches global memory now; saves one launch + full hrel round-trip.
__global__ __launch_bounds__(256) void k_gat1s2(
    const int* __restrict__ cnt, const int* __restrict__ csc,
    const int* __restrict__ row_full, const int* __restrict__ full_list,
    const int* __restrict__ nfull,
    const float* __restrict__ h1g, const float* __restrict__ es1,
    const float* __restrict__ ed1, const float* __restrict__ gat1_b,
    const float* __restrict__ W2,
    const float* __restrict__ a_s2, const float* __restrict__ a_d2,
    float* __restrict__ h2g, float* __restrict__ es2, float* __restrict__ ed2)
{
    const int tid = threadIdx.x;
    const int lc = tid >> 6;          // col in block 0..3
    const int grp = (tid >> 4) & 3;   // edge group 0..3
    const int d = tid & 15;           // h-dim 0..15
    const int j = blockIdx.x * 4 + lc;
    const float edj = ed1[j];
    float acc = 0.0f, l = 0.0f;

    const int n = min(cnt[j], CAP);
    const int* lst = csc + j * CAP;
    for (int e = grp; e < n; e += 4) {
        int i = lst[e];
        float p = lrelu_exp(es1[i] + edj);
        l += p;
        acc += p * h1g[i * GATH + d];
    }
    if (grp == 0 && !row_full[j]) {          // self edge (diag)
        float p = lrelu_exp(es1[j] + edj);
        l += p;
        acc += p * h1g[j * GATH + d];
    }
    const int nf = *nfull;                    // full rows adjacent everywhere
    for (int f = grp; f < nf; f += 4) {
        int i = full_list[f];
        float p = lrelu_exp(es1[i] + edj);
        l += p;
        acc += p * h1g[i * GATH + d];
    }

    __shared__ float sacc[4][4][GATH];
    __shared__ float sl[4][4];
    __shared__ float hl[4][GATH];     // hrel rows (LDS only, never global)
    __shared__ float h2l[4][HH];
    sacc[lc][grp][d] = acc;
    if (d == 0) sl[lc][grp] = l;
    __syncthreads();
    if (grp == 0) {
        float a = sacc[lc][0][d] + sacc[lc][1][d] + sacc[lc][2][d] + sacc[lc][3][d];
        float L = sl[lc][0] + sl[lc][1] + sl[lc][2] + sl[lc][3];
        hl[lc][d] = fmaxf(a / L + gat1_b[d], 0.0f);
    }
    __syncthreads();
    // ---- h2 matvec: thread (lc2, jj) computes h2[j2][jj] ----
    {
        const int lc2 = tid >> 6;
        const int jj = tid & 63;
        float acc2 = 0.0f;
        #pragma unroll
        for (int k = 0; k < GATH; ++k)
            acc2 += hl[lc2][k] * W2[k * HH + jj];   // W2 coalesced, L2-hot
        const int j2 = blockIdx.x * 4 + lc2;
        h2g[j2 * HH + jj] = acc2;
        h2l[lc2][jj] = acc2;
    }
    __syncthreads();
    if (tid < 4) {
        float e_s = 0.0f, e_d = 0.0f;
        #pragma unroll 16
        for (int t = 0; t < HH; ++t) {
            float hv = h2l[tid][t];
            e_s += hv * a_s2[t];
            e_d += hv * a_d2[t];
        }
        es2[blockIdx.x * 4 + tid] = e_s;
        ed2[blockIdx.x * 4 + tid] = e_d;
    }
}

// ---------- GAT2 sparse + fc + leaky_relu: 1 col/block ----------
__global__ __launch_bounds__(256) void k_gat2s(
    const int* __restrict__ cnt, const int* __restrict__ csc,
    const int* __restrict__ row_full, const int* __restrict__ full_list,
    const int* __restrict__ nfull,
    const float* __restrict__ h2g, const float* __restrict__ es2,
    const float* __restrict__ ed2, const float* __restrict__ gat2_b,
    const float* __restrict__ fc_W, const float* __restrict__ fc_b,
    float* __restrict__ out)
{
    const int tid = threadIdx.x;
    const int grp = tid >> 6;         // edge group 0..3
    const int d = tid & 63;           // h-dim 0..63
    const int j = blockIdx.x;
    const float edj = ed2[j];
    float acc = 0.0f, l = 0.0f;

    const int n = min(cnt[j], CAP);
    const int* lst = csc + j * CAP;
    for (int e = grp; e < n; e += 4) {
        int i = lst[e];
        float p = lrelu_exp(es2[i] + edj);
        l += p;
        acc += p * h2g[i * HH + d];
    }
    if (grp == 0 && !row_full[j]) {
        float p = lrelu_exp(es2[j] + edj);
        l += p;
        acc += p * h2g[j * HH + d];
    }
    const int nf = *nfull;
    for (int f = grp; f < nf; f += 4) {
        int i = full_list[f];
        float p = lrelu_exp(es2[i] + edj);
        l += p;
        acc += p * h2g[i * HH + d];
    }

    __shared__ float sacc[4][HH];
    __shared__ float sl[4];
    sacc[grp][d] = acc;
    if (d == 0) sl[grp] = l;
    __syncthreads();
    if (grp == 0) {                    // tid 0..63 = one wave
        float a = sacc[0][d] + sacc[1][d] + sacc[2][d] + sacc[3][d];
        float L = sl[0] + sl[1] + sl[2] + sl[3];
        float v = a / L + gat2_b[d];
        float t = v * fc_W[d];
        #pragma unroll
        for (int off = 32; off >= 1; off >>= 1)
            t += __shfl_down(t, off, 64);
        if (d == 0) {
            float r = t + fc_b[0];
            out[j] = (r > 0.0f) ? r : 0.2f * r;
        }
    }
}

extern "C" void kernel_launch(void* const* d_in, const int* in_sizes, int n_in,
                              void* d_out, int out_size, void* d_ws, size_t ws_size,
                              hipStream_t stream)
{
    const float* inputs   = (const float*)d_in[0];
    // d_in[1] (relation), d_in[3] (rel_w_W), d_in[4] (rel_w_b) are dead:
    // softmax(rel_mask + weight) > 0 depends only on rel_mask.
    const float* rel_mask = (const float*)d_in[2];
    const float* w_ih0 = (const float*)d_in[5];
    const float* w_hh0 = (const float*)d_in[6];
    const float* b_ih0 = (const float*)d_in[7];
    const float* b_hh0 = (const float*)d_in[8];
    const float* w_ih1 = (const float*)d_in[9];
    const float* w_hh1 = (const float*)d_in[10];
    const float* b_ih1 = (const float*)d_in[11];
    const float* b_hh1 = (const float*)d_in[12];
    const float* gat1_W  = (const float*)d_in[13];
    const float* gat1_as = (const float*)d_in[14];
    const float* gat1_ad = (const float*)d_in[15];
    const float* gat1_b  = (const float*)d_in[16];
    const float* gat2_W  = (const float*)d_in[17];
    const float* gat2_as = (const float*)d_in[18];
    const float* gat2_ad = (const float*)d_in[19];
    const float* gat2_b  = (const float*)d_in[20];
    const float* fc_W = (const float*)d_in[21];
    const float* fc_b = (const float*)d_in[22];
    float* out = (float*)d_out;

    float* ws = (float*)d_ws;
    float* x_out = ws;                       // 2048*64
    float* h1g = x_out + NN * HH;            // 2048*16
    float* es1 = h1g + NN * GATH;            // 2048
    float* ed1 = es1 + NN;                   // 2048
    float* hrel = ed1 + NN;                  // 2048*16 (unused since R12)
    float* h2g = hrel + NN * GATH;           // 2048*64
    float* es2 = h2g + NN * HH;              // 2048
    float* ed2 = es2 + NN;                   // 2048
    int* cnt = (int*)(ed2 + NN);             // 2048
    int* row_full = cnt + NN;                // 2048
    int* full_list = row_full + NN;          // 2048
    int* nfull = full_list + NN;             // 1 (+pad)
    int* csc = nfull + 8;                    // 2048*CAP = 2 MB

    k_zero<<<(NN + 255) / 256, 256, 0, stream>>>(cnt, nfull);
    k_lstm_edges<<<NN, 256, 0, stream>>>(inputs, w_ih0, w_hh0, b_ih0, b_hh0,
                                         w_ih1, w_hh1, b_ih1, b_hh1, x_out,
                                         rel_mask, cnt, csc, row_full,
                                         full_list, nfull);
    k_h1<<<NN / 16, 256, 0, stream>>>(x_out, gat1_W, gat1_as, gat1_ad, h1g, es1, ed1);
    k_gat1s2<<<NN / 4, 256, 0, stream>>>(cnt, csc, row_full, full_list, nfull,
                                         h1g, es1, ed1, gat1_b,
                                         gat2_W, gat2_as, gat2_ad,
                                         h2g, es2, ed2);
    k_gat2s<<<NN, 256, 0, stream>>>(cnt, csc, row_full, full_list, nfull,
                                    h2g, es2, ed2, gat2_b, fc_W, fc_b, out);
}

// Round 7
// 463.011 us; speedup vs baseline: 5.9987x; 1.2946x over previous
//
#include <hip/hip_runtime.h>
#include <math.h>

#define NN 2048
#define TT 32
#define FIN 5
#define HH 64
#define G4 256     // 4*H
#define GATH 16
#define CAP 256    // max CSC edges/column: mean 102, sigma ~10 -> +15 sigma safe

// ---------- helpers ----------
__device__ __forceinline__ float sigf(float x) {
    return 1.0f / (1.0f + __expf(-x));
}
__device__ __forceinline__ float tanh_fast(float x) {
    x = fminf(fmaxf(x, -15.0f), 15.0f);
    float t = __expf(2.0f * x);
    return (t - 1.0f) / (t + 1.0f);
}
__device__ __forceinline__ float dot4(float4 a, float4 b) {
    return a.x * b.x + a.y * b.y + a.z * b.z + a.w * b.w;
}
__device__ __forceinline__ float lrelu_exp(float x) {
    x = (x > 0.0f) ? x : 0.2f * x;
    return __expf(x);
}

// ---------- zero the edge-build counters ----------
__global__ void k_zero(int* __restrict__ cnt, int* __restrict__ nfull)
{
    int i = blockIdx.x * 256 + threadIdx.x;
    if (i < NN) cnt[i] = 0;
    if (i == 0) *nfull = 0;
}

// ---------- fused: edge-scan prologue + 2-layer LSTM + h1/es1/ed1 epilogue -
// R14 = R13 resubmitted verbatim (R13's bench was an infra container
// failure, no kernel evidence). Design rationale:
// R12's block-partition fusion ran the grid in TWO residency batches
// (2048 blocks, same blocks/CU -> 2x202=385us). Fix: SAME-block fusion,
// grid stays 1024 (fully co-resident like R7's 202.7us):
//  * prologue: each block scans rel_mask rows of its own 2 nodes (16
//    floats/thread, hides under phase-A weight loads);
//  * LSTM body: R7 verbatim;
//  * epilogue: h1 = x@gat1_W + es1/ed1 from h1_lds (x_out fed ONLY k_h1,
//    so the global round-trip and the k_h1 launch are deleted).
#define LNB 2
__global__ __launch_bounds__(256, 1)
void k_lstm_eh(
    const float* __restrict__ inputs,
    const float* __restrict__ w_ih0, const float* __restrict__ w_hh0,
    const float* __restrict__ b_ih0, const float* __restrict__ b_hh0,
    const float* __restrict__ w_ih1, const float* __restrict__ w_hh1,
    const float* __restrict__ b_ih1, const float* __restrict__ b_hh1,
    const float* __restrict__ rel_mask,
    int* __restrict__ cnt, int* __restrict__ csc,
    int* __restrict__ row_full, int* __restrict__ full_list,
    int* __restrict__ nfull,
    const float* __restrict__ gat1_W,
    const float* __restrict__ gat1_as, const float* __restrict__ gat1_ad,
    float* __restrict__ h1g, float* __restrict__ es1, float* __restrict__ ed1)
{
    __shared__ float x_lds[LNB * TT * FIN];        // 320 f
    __shared__ float hist[LNB][TT + 1][HH];        // 4224 f = 16.9 KB
    __shared__ float g_lds[LNB * G4];              // 512 f
    __shared__ float h1_lds[LNB * HH];             // 128 f
    __shared__ float Wl[HH * GATH];                // 1024 f (gat1_W staged)
    __shared__ float h1l[LNB][GATH];
    __shared__ int s_any[LNB];

    const int tid = threadIdx.x;
    const int n0 = blockIdx.x * LNB;
    const int g = tid;                 // gate row 0..255
    const int cnb = tid >> 6;          // combine: node (tid<128): 0..1
    const int ck = tid & 63;           // combine: cell 0..63

    for (int idx = tid; idx < LNB * TT * FIN; idx += 256)
        x_lds[idx] = inputs[n0 * (TT * FIN) + idx];
    for (int idx = tid; idx < HH * GATH; idx += 256)
        Wl[idx] = gat1_W[idx];
    if (tid < LNB * HH) {
        hist[tid >> 6][0][tid & 63] = 0.0f;
        h1_lds[tid] = 0.0f;
    }
    if (tid < LNB) s_any[tid] = 0;
    __syncthreads();

    // ---- edge prologue: scan rel_mask rows n0, n0+1 (this block's nodes) --
    {
        bool m0 = false, m1 = false;
        for (int j = tid; j < NN; j += 256) {
            float rm0 = rel_mask[(n0 + 0) * NN + j];
            float rm1 = rel_mask[(n0 + 1) * NN + j];
            bool e0 = (rm0 == 0.0f);
            bool e1 = (rm1 == 0.0f);
            m0 |= e0;
            m1 |= e1;
            if (e0 && j != n0) {
                int slot = atomicAdd(&cnt[j], 1);
                if (slot < CAP) csc[j * CAP + slot] = n0;
            }
            if (e1 && j != n0 + 1) {
                int slot = atomicAdd(&cnt[j], 1);
                if (slot < CAP) csc[j * CAP + slot] = n0 + 1;
            }
        }
        if (m0) atomicOr(&s_any[0], 1);
        if (m1) atomicOr(&s_any[1], 1);
        __syncthreads();
        if (tid < LNB) {
            const int i = n0 + tid;
            int any = s_any[tid];
            row_full[i] = any ? 0 : 1;
            if (!any) {
                int k = atomicAdd(nfull, 1);
                full_list[k] = i;
            }
        }
    }

    // ================= Phase A: layer 0 (R7 verbatim) =================
    {
        float4 w0[16];
        {
            const float4* p = (const float4*)(w_hh0 + g * HH);
            #pragma unroll
            for (int k = 0; k < 16; ++k) w0[k] = p[k];
        }
        float xw0 = w_ih0[g * FIN + 0];
        float xw1 = w_ih0[g * FIN + 1];
        float xw2 = w_ih0[g * FIN + 2];
        float xw3 = w_ih0[g * FIN + 3];
        float xw4 = w_ih0[g * FIN + 4];
        const float bias0 = b_ih0[g] + b_hh0[g];
        float cA = 0.0f;

        __syncthreads();

        for (int t = 1; t <= TT; ++t) {
            #pragma unroll
            for (int nb = 0; nb < LNB; ++nb) {
                const float4* hv = (const float4*)&hist[nb][t - 1][0];
                float s0 = 0.f, s1 = 0.f, s2 = 0.f, s3 = 0.f;
                #pragma unroll
                for (int k = 0; k < 4; ++k) {
                    s0 += dot4(w0[k],      hv[k]);
                    s1 += dot4(w0[4 + k],  hv[4 + k]);
                    s2 += dot4(w0[8 + k],  hv[8 + k]);
                    s3 += dot4(w0[12 + k], hv[12 + k]);
                }
                const float* xv = &x_lds[nb * (TT * FIN) + (t - 1) * FIN];
                float a = bias0 + xw0 * xv[0] + xw1 * xv[1] + xw2 * xv[2] +
                          xw3 * xv[3] + xw4 * xv[4];
                g_lds[nb * G4 + g] = a + (s0 + s1) + (s2 + s3);
            }
            __syncthreads();
            if (tid < LNB * HH) {
                const int base = cnb * G4 + ck;
                float gi = g_lds[base];
                float gf = g_lds[base + 64];
                float gg = g_lds[base + 128];
                float go = g_lds[base + 192];
                cA = sigf(gf) * cA + sigf(gi) * tanh_fast(gg);
                hist[cnb][t][ck] = sigf(go) * tanh_fast(cA);
            }
            __syncthreads();
        }
    }

    // ================= Phase B: layer 1 (R7 verbatim) =================
    {
        float4 wi[16], wh[16];
        {
            const float4* pi = (const float4*)(w_ih1 + g * HH);
            const float4* ph = (const float4*)(w_hh1 + g * HH);
            #pragma unroll
            for (int k = 0; k < 16; ++k) { wi[k] = pi[k]; wh[k] = ph[k]; }
        }
        const float bias1 = b_ih1[g] + b_hh1[g];
        float cA = 0.0f;

        for (int t = 1; t <= TT; ++t) {
            #pragma unroll
            for (int nb = 0; nb < LNB; ++nb) {
                const float4* xv = (const float4*)&hist[nb][t][0];
                const float4* hv = (const float4*)&h1_lds[nb * HH];
                float s0 = 0.f, s1 = 0.f, s2 = 0.f, s3 = 0.f;
                float u0 = 0.f, u1 = 0.f, u2 = 0.f, u3 = 0.f;
                #pragma unroll
                for (int k = 0; k < 4; ++k) {
                    s0 += dot4(wi[k],      xv[k]);
                    s1 += dot4(wi[4 + k],  xv[4 + k]);
                    s2 += dot4(wi[8 + k],  xv[8 + k]);
                    s3 += dot4(wi[12 + k], xv[12 + k]);
                    u0 += dot4(wh[k],      hv[k]);
                    u1 += dot4(wh[4 + k],  hv[4 + k]);
                    u2 += dot4(wh[8 + k],  hv[8 + k]);
                    u3 += dot4(wh[12 + k], hv[12 + k]);
                }
                g_lds[nb * G4 + g] =
                    bias1 + ((s0 + s1) + (s2 + s3)) + ((u0 + u1) + (u2 + u3));
            }
            __syncthreads();
            if (tid < LNB * HH) {
                const int base = cnb * G4 + ck;
                float gi = g_lds[base];
                float gf = g_lds[base + 64];
                float gg = g_lds[base + 128];
                float go = g_lds[base + 192];
                cA = sigf(gf) * cA + sigf(gi) * tanh_fast(gg);
                h1_lds[cnb * HH + ck] = sigf(go) * tanh_fast(cA);
            }
            __syncthreads();
        }
    }

    // ---- epilogue: h1 = x @ gat1_W ; es1/ed1 (x never leaves LDS) ----
    if (tid < LNB * GATH) {            // 32 threads, 64-len dots
        const int ln = tid >> 4, dd = tid & 15;
        float acc = 0.0f;
        #pragma unroll 16
        for (int k = 0; k < HH; ++k)
            acc += h1_lds[ln * HH + k] * Wl[k * GATH + dd];
        h1g[(n0 + ln) * GATH + dd] = acc;
        h1l[ln][dd] = acc;
    }
    __syncthreads();
    if (tid < LNB) {
        float e_s = 0.0f, e_d = 0.0f;
        #pragma unroll
        for (int t = 0; t < GATH; ++t) {
            float hv = h1l[tid][t];
            e_s += hv * gat1_as[t];
            e_d += hv * gat1_ad[t];
        }
        es1[n0 + tid] = e_s;
        ed1[n0 + tid] = e_d;
    }
}

// ---------- fused GAT1 sparse + h2 = relu(hrel) @ gat2_W + es2/ed2 --------
// hrel feeds ONLY h2, so it never touches global memory (R12 win, kept).
__global__ __launch_bounds__(256) void k_gat1s2(
    const int* __restrict__ cnt, const int* __restrict__ csc,
    const int* __restrict__ row_full, const int* __restrict__ full_list,
    const int* __restrict__ nfull,
    const float* __restrict__ h1g, const float* __restrict__ es1,
    const float* __restrict__ ed1, const float* __restrict__ gat1_b,
    const float* __restrict__ W2,
    const float* __restrict__ a_s2, const float* __restrict__ a_d2,
    float* __restrict__ h2g, float* __restrict__ es2, float* __restrict__ ed2)
{
    const int tid = threadIdx.x;
    const int lc = tid >> 6;          // col in block 0..3
    const int grp = (tid >> 4) & 3;   // edge group 0..3
    const int d = tid & 15;           // h-dim 0..15
    const int j = blockIdx.x * 4 + lc;
    const float edj = ed1[j];
    float acc = 0.0f, l = 0.0f;

    const int n = min(cnt[j], CAP);
    const int* lst = csc + j * CAP;
    for (int e = grp; e < n; e += 4) {
        int i = lst[e];
        float p = lrelu_exp(es1[i] + edj);
        l += p;
        acc += p * h1g[i * GATH + d];
    }
    if (grp == 0 && !row_full[j]) {          // self edge (diag)
        float p = lrelu_exp(es1[j] + edj);
        l += p;
        acc += p * h1g[j * GATH + d];
    }
    const int nf = *nfull;                    // full rows adjacent everywhere
    for (int f = grp; f < nf; f += 4) {
        int i = full_list[f];
        float p = lrelu_exp(es1[i] + edj);
        l += p;
        acc += p * h1g[i * GATH + d];
    }

    __shared__ float sacc[4][4][GATH];
    __shared__ float sl[4][4];
    __shared__ float hl[4][GATH];     // hrel rows (LDS only, never global)
    __shared__ float h2l[4][HH];
    sacc[lc][grp][d] = acc;
    if (d == 0) sl[lc][grp] = l;
    __syncthreads();
    if (grp == 0) {
        float a = sacc[lc][0][d] + sacc[lc][1][d] + sacc[lc][2][d] + sacc[lc][3][d];
        float L = sl[lc][0] + sl[lc][1] + sl[lc][2] + sl[lc][3];
        hl[lc][d] = fmaxf(a / L + gat1_b[d], 0.0f);
    }
    __syncthreads();
    // ---- h2 matvec: thread (lc2, jj) computes h2[j2][jj] ----
    {
        const int lc2 = tid >> 6;
        const int jj = tid & 63;
        float acc2 = 0.0f;
        #pragma unroll
        for (int k = 0; k < GATH; ++k)
            acc2 += hl[lc2][k] * W2[k * HH + jj];   // W2 coalesced, L2-hot
        const int j2 = blockIdx.x * 4 + lc2;
        h2g[j2 * HH + jj] = acc2;
        h2l[lc2][jj] = acc2;
    }
    __syncthreads();
    if (tid < 4) {
        float e_s = 0.0f, e_d = 0.0f;
        #pragma unroll 16
        for (int t = 0; t < HH; ++t) {
            float hv = h2l[tid][t];
            e_s += hv * a_s2[t];
            e_d += hv * a_d2[t];
        }
        es2[blockIdx.x * 4 + tid] = e_s;
        ed2[blockIdx.x * 4 + tid] = e_d;
    }
}

// ---------- GAT2 sparse + fc + leaky_relu: 1 col/block ----------
__global__ __launch_bounds__(256) void k_gat2s(
    const int* __restrict__ cnt, const int* __restrict__ csc,
    const int* __restrict__ row_full, const int* __restrict__ full_list,
    const int* __restrict__ nfull,
    const float* __restrict__ h2g, const float* __restrict__ es2,
    const float* __restrict__ ed2, const float* __restrict__ gat2_b,
    const float* __restrict__ fc_W, const float* __restrict__ fc_b,
    float* __restrict__ out)
{
    const int tid = threadIdx.x;
    const int grp = tid >> 6;         // edge group 0..3
    const int d = tid & 63;           // h-dim 0..63
    const int j = blockIdx.x;
    const float edj = ed2[j];
    float acc = 0.0f, l = 0.0f;

    const int n = min(cnt[j], CAP);
    const int* lst = csc + j * CAP;
    for (int e = grp; e < n; e += 4) {
        int i = lst[e];
        float p = lrelu_exp(es2[i] + edj);
        l += p;
        acc += p * h2g[i * HH + d];
    }
    if (grp == 0 && !row_full[j]) {
        float p = lrelu_exp(es2[j] + edj);
        l += p;
        acc += p * h2g[j * HH + d];
    }
    const int nf = *nfull;
    for (int f = grp; f < nf; f += 4) {
        int i = full_list[f];
        float p = lrelu_exp(es2[i] + edj);
        l += p;
        acc += p * h2g[i * HH + d];
    }

    __shared__ float sacc[4][HH];
    __shared__ float sl[4];
    sacc[grp][d] = acc;
    if (d == 0) sl[grp] = l;
    __syncthreads();
    if (grp == 0) {                    // tid 0..63 = one wave
        float a = sacc[0][d] + sacc[1][d] + sacc[2][d] + sacc[3][d];
        float L = sl[0] + sl[1] + sl[2] + sl[3];
        float v = a / L + gat2_b[d];
        float t = v * fc_W[d];
        #pragma unroll
        for (int off = 32; off >= 1; off >>= 1)
            t += __shfl_down(t, off, 64);
        if (d == 0) {
            float r = t + fc_b[0];
            out[j] = (r > 0.0f) ? r : 0.2f * r;
        }
    }
}

extern "C" void kernel_launch(void* const* d_in, const int* in_sizes, int n_in,
                              void* d_out, int out_size, void* d_ws, size_t ws_size,
                              hipStream_t stream)
{
    const float* inputs   = (const float*)d_in[0];
    // d_in[1] (relation), d_in[3] (rel_w_W), d_in[4] (rel_w_b) are dead:
    // softmax(rel_mask + weight) > 0 depends only on rel_mask.
    const float* rel_mask = (const float*)d_in[2];
    const float* w_ih0 = (const float*)d_in[5];
    const float* w_hh0 = (const float*)d_in[6];
    const float* b_ih0 = (const float*)d_in[7];
    const float* b_hh0 = (const float*)d_in[8];
    const float* w_ih1 = (const float*)d_in[9];
    const float* w_hh1 = (const float*)d_in[10];
    const float* b_ih1 = (const float*)d_in[11];
    const float* b_hh1 = (const float*)d_in[12];
    const float* gat1_W  = (const float*)d_in[13];
    const float* gat1_as = (const float*)d_in[14];
    const float* gat1_ad = (const float*)d_in[15];
    const float* gat1_b  = (const float*)d_in[16];
    const float* gat2_W  = (const float*)d_in[17];
    const float* gat2_as = (const float*)d_in[18];
    const float* gat2_ad = (const float*)d_in[19];
    const float* gat2_b  = (const float*)d_in[20];
    const float* fc_W = (const float*)d_in[21];
    const float* fc_b = (const float*)d_in[22];
    float* out = (float*)d_out;

    float* ws = (float*)d_ws;
    float* x_out = ws;                       // 2048*64 (unused since R13)
    float* h1g = x_out + NN * HH;            // 2048*16
    float* es1 = h1g + NN * GATH;            // 2048
    float* ed1 = es1 + NN;                   // 2048
    float* hrel = ed1 + NN;                  // 2048*16 (unused since R12)
    float* h2g = hrel + NN * GATH;           // 2048*64
    float* es2 = h2g + NN * HH;              // 2048
    float* ed2 = es2 + NN;                   // 2048
    int* cnt = (int*)(ed2 + NN);             // 2048
    int* row_full = cnt + NN;                // 2048
    int* full_list = row_full + NN;          // 2048
    int* nfull = full_list + NN;             // 1 (+pad)
    int* csc = nfull + 8;                    // 2048*CAP = 2 MB

    k_zero<<<(NN + 255) / 256, 256, 0, stream>>>(cnt, nfull);
    k_lstm_eh<<<NN / LNB, 256, 0, stream>>>(inputs, w_ih0, w_hh0, b_ih0, b_hh0,
                                            w_ih1, w_hh1, b_ih1, b_hh1,
                                            rel_mask, cnt, csc, row_full,
                                            full_list, nfull,
                                            gat1_W, gat1_as, gat1_ad,
                                            h1g, es1, ed1);
    k_gat1s2<<<NN / 4, 256, 0, stream>>>(cnt, csc, row_full, full_list, nfull,
                                         h1g, es1, ed1, gat1_b,
                                         gat2_W, gat2_as, gat2_ad,
                                         h2g, es2, ed2);
    k_gat2s<<<NN, 256, 0, stream>>>(cnt, csc, row_full, full_list, nfull,
                                    h2g, es2, ed2, gat2_b, fc_W, fc_b, out);
}

// Round 8
// 450.755 us; speedup vs baseline: 6.1618x; 1.0272x over previous
//
#include <hip/hip_runtime.h>
#include <math.h>

#define NN 2048
#define TT 32
#define FIN 5
#define HH 64
#define G4 256     // 4*H
#define GATH 16
#define CAP 256    // max CSC edges/column: mean 102, sigma ~10 -> +15 sigma safe

// ---------- helpers ----------
__device__ __forceinline__ float sigf(float x) {
    return 1.0f / (1.0f + __expf(-x));
}
__device__ __forceinline__ float tanh_fast(float x) {
    x = fminf(fmaxf(x, -15.0f), 15.0f);
    float t = __expf(2.0f * x);
    return (t - 1.0f) / (t + 1.0f);
}
__device__ __forceinline__ float dot4(float4 a, float4 b) {
    return a.x * b.x + a.y * b.y + a.z * b.z + a.w * b.w;
}
__device__ __forceinline__ float lrelu_exp(float x) {
    x = (x > 0.0f) ? x : 0.2f * x;
    return __expf(x);
}

// ---------- zero the edge-build counters ----------
__global__ void k_zero(int* __restrict__ cnt, int* __restrict__ nfull)
{
    int i = blockIdx.x * 256 + threadIdx.x;
    if (i < NN) cnt[i] = 0;
    if (i == 0) *nfull = 0;
}

// ---------- fused: edge-scan prologue + 2-layer LSTM + h1/es1/ed1 epilogue -
// R14 body kept VERBATIM (251 us measured, absmax 0.0).
#define LNB 2
__global__ __launch_bounds__(256, 1)
void k_lstm_eh(
    const float* __restrict__ inputs,
    const float* __restrict__ w_ih0, const float* __restrict__ w_hh0,
    const float* __restrict__ b_ih0, const float* __restrict__ b_hh0,
    const float* __restrict__ w_ih1, const float* __restrict__ w_hh1,
    const float* __restrict__ b_ih1, const float* __restrict__ b_hh1,
    const float* __restrict__ rel_mask,
    int* __restrict__ cnt, int* __restrict__ csc,
    int* __restrict__ row_full, int* __restrict__ full_list,
    int* __restrict__ nfull,
    const float* __restrict__ gat1_W,
    const float* __restrict__ gat1_as, const float* __restrict__ gat1_ad,
    float* __restrict__ h1g, float* __restrict__ es1, float* __restrict__ ed1)
{
    __shared__ float x_lds[LNB * TT * FIN];        // 320 f
    __shared__ float hist[LNB][TT + 1][HH];        // 4224 f = 16.9 KB
    __shared__ float g_lds[LNB * G4];              // 512 f
    __shared__ float h1_lds[LNB * HH];             // 128 f
    __shared__ float Wl[HH * GATH];                // 1024 f (gat1_W staged)
    __shared__ float h1l[LNB][GATH];
    __shared__ int s_any[LNB];

    const int tid = threadIdx.x;
    const int n0 = blockIdx.x * LNB;
    const int g = tid;                 // gate row 0..255
    const int cnb = tid >> 6;          // combine: node (tid<128): 0..1
    const int ck = tid & 63;           // combine: cell 0..63

    for (int idx = tid; idx < LNB * TT * FIN; idx += 256)
        x_lds[idx] = inputs[n0 * (TT * FIN) + idx];
    for (int idx = tid; idx < HH * GATH; idx += 256)
        Wl[idx] = gat1_W[idx];
    if (tid < LNB * HH) {
        hist[tid >> 6][0][tid & 63] = 0.0f;
        h1_lds[tid] = 0.0f;
    }
    if (tid < LNB) s_any[tid] = 0;
    __syncthreads();

    // ---- edge prologue: scan rel_mask rows n0, n0+1 (this block's nodes) --
    {
        bool m0 = false, m1 = false;
        for (int j = tid; j < NN; j += 256) {
            float rm0 = rel_mask[(n0 + 0) * NN + j];
            float rm1 = rel_mask[(n0 + 1) * NN + j];
            bool e0 = (rm0 == 0.0f);
            bool e1 = (rm1 == 0.0f);
            m0 |= e0;
            m1 |= e1;
            if (e0 && j != n0) {
                int slot = atomicAdd(&cnt[j], 1);
                if (slot < CAP) csc[j * CAP + slot] = n0;
            }
            if (e1 && j != n0 + 1) {
                int slot = atomicAdd(&cnt[j], 1);
                if (slot < CAP) csc[j * CAP + slot] = n0 + 1;
            }
        }
        if (m0) atomicOr(&s_any[0], 1);
        if (m1) atomicOr(&s_any[1], 1);
        __syncthreads();
        if (tid < LNB) {
            const int i = n0 + tid;
            int any = s_any[tid];
            row_full[i] = any ? 0 : 1;
            if (!any) {
                int k = atomicAdd(nfull, 1);
                full_list[k] = i;
            }
        }
    }

    // ================= Phase A: layer 0 (R7 verbatim) =================
    {
        float4 w0[16];
        {
            const float4* p = (const float4*)(w_hh0 + g * HH);
            #pragma unroll
            for (int k = 0; k < 16; ++k) w0[k] = p[k];
        }
        float xw0 = w_ih0[g * FIN + 0];
        float xw1 = w_ih0[g * FIN + 1];
        float xw2 = w_ih0[g * FIN + 2];
        float xw3 = w_ih0[g * FIN + 3];
        float xw4 = w_ih0[g * FIN + 4];
        const float bias0 = b_ih0[g] + b_hh0[g];
        float cA = 0.0f;

        __syncthreads();

        for (int t = 1; t <= TT; ++t) {
            #pragma unroll
            for (int nb = 0; nb < LNB; ++nb) {
                const float4* hv = (const float4*)&hist[nb][t - 1][0];
                float s0 = 0.f, s1 = 0.f, s2 = 0.f, s3 = 0.f;
                #pragma unroll
                for (int k = 0; k < 4; ++k) {
                    s0 += dot4(w0[k],      hv[k]);
                    s1 += dot4(w0[4 + k],  hv[4 + k]);
                    s2 += dot4(w0[8 + k],  hv[8 + k]);
                    s3 += dot4(w0[12 + k], hv[12 + k]);
                }
                const float* xv = &x_lds[nb * (TT * FIN) + (t - 1) * FIN];
                float a = bias0 + xw0 * xv[0] + xw1 * xv[1] + xw2 * xv[2] +
                          xw3 * xv[3] + xw4 * xv[4];
                g_lds[nb * G4 + g] = a + (s0 + s1) + (s2 + s3);
            }
            __syncthreads();
            if (tid < LNB * HH) {
                const int base = cnb * G4 + ck;
                float gi = g_lds[base];
                float gf = g_lds[base + 64];
                float gg = g_lds[base + 128];
                float go = g_lds[base + 192];
                cA = sigf(gf) * cA + sigf(gi) * tanh_fast(gg);
                hist[cnb][t][ck] = sigf(go) * tanh_fast(cA);
            }
            __syncthreads();
        }
    }

    // ================= Phase B: layer 1 (R7 verbatim) =================
    {
        float4 wi[16], wh[16];
        {
            const float4* pi = (const float4*)(w_ih1 + g * HH);
            const float4* ph = (const float4*)(w_hh1 + g * HH);
            #pragma unroll
            for (int k = 0; k < 16; ++k) { wi[k] = pi[k]; wh[k] = ph[k]; }
        }
        const float bias1 = b_ih1[g] + b_hh1[g];
        float cA = 0.0f;

        for (int t = 1; t <= TT; ++t) {
            #pragma unroll
            for (int nb = 0; nb < LNB; ++nb) {
                const float4* xv = (const float4*)&hist[nb][t][0];
                const float4* hv = (const float4*)&h1_lds[nb * HH];
                float s0 = 0.f, s1 = 0.f, s2 = 0.f, s3 = 0.f;
                float u0 = 0.f, u1 = 0.f, u2 = 0.f, u3 = 0.f;
                #pragma unroll
                for (int k = 0; k < 4; ++k) {
                    s0 += dot4(wi[k],      xv[k]);
                    s1 += dot4(wi[4 + k],  xv[4 + k]);
                    s2 += dot4(wi[8 + k],  xv[8 + k]);
                    s3 += dot4(wi[12 + k], xv[12 + k]);
                    u0 += dot4(wh[k],      hv[k]);
                    u1 += dot4(wh[4 + k],  hv[4 + k]);
                    u2 += dot4(wh[8 + k],  hv[8 + k]);
                    u3 += dot4(wh[12 + k], hv[12 + k]);
                }
                g_lds[nb * G4 + g] =
                    bias1 + ((s0 + s1) + (s2 + s3)) + ((u0 + u1) + (u2 + u3));
            }
            __syncthreads();
            if (tid < LNB * HH) {
                const int base = cnb * G4 + ck;
                float gi = g_lds[base];
                float gf = g_lds[base + 64];
                float gg = g_lds[base + 128];
                float go = g_lds[base + 192];
                cA = sigf(gf) * cA + sigf(gi) * tanh_fast(gg);
                h1_lds[cnb * HH + ck] = sigf(go) * tanh_fast(cA);
            }
            __syncthreads();
        }
    }

    // ---- epilogue: h1 = x @ gat1_W ; es1/ed1 (x never leaves LDS) ----
    if (tid < LNB * GATH) {            // 32 threads, 64-len dots
        const int ln = tid >> 4, dd = tid & 15;
        float acc = 0.0f;
        #pragma unroll 16
        for (int k = 0; k < HH; ++k)
            acc += h1_lds[ln * HH + k] * Wl[k * GATH + dd];
        h1g[(n0 + ln) * GATH + dd] = acc;
        h1l[ln][dd] = acc;
    }
    __syncthreads();
    if (tid < LNB) {
        float e_s = 0.0f, e_d = 0.0f;
        #pragma unroll
        for (int t = 0; t < GATH; ++t) {
            float hv = h1l[tid][t];
            e_s += hv * gat1_as[t];
            e_d += hv * gat1_ad[t];
        }
        es1[n0 + tid] = e_s;
        ed1[n0 + tid] = e_d;
    }
}

// ---------- GAT1 + h2 + es2/ed2, chain-broken -----------------------------
// R15: stage 1 fills p/idx for ALL edges in parallel (coalesced csc read,
// one exp per edge instead of per (edge,d)); stage 2 is a pure streaming
// accumulate over LDS-cached p/idx with only the coalesced h1g-row read
// going to memory (iterations independent -> unroll-4 keeps 4 row loads
// in flight). Self/full-row entries are appended into the same arrays so
// the hot loop has no special cases.
__global__ __launch_bounds__(256) void k_gat1s2(
    const int* __restrict__ cnt, const int* __restrict__ csc,
    const int* __restrict__ row_full, const int* __restrict__ full_list,
    const int* __restrict__ nfull,
    const float* __restrict__ h1g, const float* __restrict__ es1,
    const float* __restrict__ ed1, const float* __restrict__ gat1_b,
    const float* __restrict__ W2,
    const float* __restrict__ a_s2, const float* __restrict__ a_d2,
    float* __restrict__ h2g, float* __restrict__ es2, float* __restrict__ ed2)
{
    const int tid = threadIdx.x;
    const int jb = blockIdx.x * 4;

    __shared__ float p_l[4][CAP + 8];
    __shared__ unsigned short idx_l[4][CAP + 8];
    __shared__ int n_tot[4];
    __shared__ float sacc[4][4][GATH];
    __shared__ float sl[4][4];
    __shared__ float hl[4][GATH];     // hrel rows (LDS only, never global)
    __shared__ float h2l[4][HH];

    // ---- stage 1: fill p/idx (all edges in parallel, coalesced csc) ----
    #pragma unroll
    for (int c = 0; c < 4; ++c) {
        const int j = jb + c;
        const float edj = ed1[j];
        const int n = min(cnt[j], CAP);
        for (int e = tid; e < n; e += 256) {
            int i = csc[j * CAP + e];
            idx_l[c][e] = (unsigned short)i;
            p_l[c][e] = lrelu_exp(es1[i] + edj);
        }
    }
    if (tid < 4) {                     // append self + full rows
        const int c = tid, j = jb + c;
        const float edj = ed1[j];
        int m = min(cnt[j], CAP);
        if (!row_full[j]) {
            idx_l[c][m] = (unsigned short)j;
            p_l[c][m] = lrelu_exp(es1[j] + edj);
            ++m;
        }
        const int nf = *nfull;
        for (int f = 0; f < nf && m < CAP + 8; ++f) {
            int i = full_list[f];
            idx_l[c][m] = (unsigned short)i;
            p_l[c][m] = lrelu_exp(es1[i] + edj);
            ++m;
        }
        n_tot[c] = m;
    }
    __syncthreads();

    // ---- stage 2: streaming accumulate ----
    const int lc = tid >> 6;          // col in block 0..3
    const int grp = (tid >> 4) & 3;   // edge group 0..3
    const int d = tid & 15;           // h-dim 0..15
    {
        const int m = n_tot[lc];
        float acc = 0.0f, l = 0.0f;
        #pragma unroll 4
        for (int e = grp; e < m; e += 4) {
            float p = p_l[lc][e];
            int i = idx_l[lc][e];
            l += p;
            acc += p * h1g[i * GATH + d];
        }
        sacc[lc][grp][d] = acc;
        if (d == 0) sl[lc][grp] = l;
    }
    __syncthreads();

    // ---- stage 3: combine -> hrel (LDS only) ----
    if (grp == 0) {
        float a = sacc[lc][0][d] + sacc[lc][1][d] + sacc[lc][2][d] + sacc[lc][3][d];
        float L = sl[lc][0] + sl[lc][1] + sl[lc][2] + sl[lc][3];
        hl[lc][d] = fmaxf(a / L + gat1_b[d], 0.0f);
    }
    __syncthreads();

    // ---- h2 matvec: thread (lc2, jj) computes h2[j2][jj] ----
    {
        const int lc2 = tid >> 6;
        const int jj = tid & 63;
        float acc2 = 0.0f;
        #pragma unroll
        for (int k = 0; k < GATH; ++k)
            acc2 += hl[lc2][k] * W2[k * HH + jj];   // W2 coalesced, L2-hot
        const int j2 = jb + lc2;
        h2g[j2 * HH + jj] = acc2;
        h2l[lc2][jj] = acc2;
    }
    __syncthreads();
    if (tid < 4) {
        float e_s = 0.0f, e_d = 0.0f;
        #pragma unroll 16
        for (int t = 0; t < HH; ++t) {
            float hv = h2l[tid][t];
            e_s += hv * a_s2[t];
            e_d += hv * a_d2[t];
        }
        es2[jb + tid] = e_s;
        ed2[jb + tid] = e_d;
    }
}

// ---------- GAT2 + fc + leaky_relu, chain-broken: 1 col/block -------------
__global__ __launch_bounds__(256) void k_gat2s(
    const int* __restrict__ cnt, const int* __restrict__ csc,
    const int* __restrict__ row_full, const int* __restrict__ full_list,
    const int* __restrict__ nfull,
    const float* __restrict__ h2g, const float* __restrict__ es2,
    const float* __restrict__ ed2, const float* __restrict__ gat2_b,
    const float* __restrict__ fc_W, const float* __restrict__ fc_b,
    float* __restrict__ out)
{
    const int tid = threadIdx.x;
    const int j = blockIdx.x;

    __shared__ float p_l[CAP + 8];
    __shared__ unsigned short idx_l[CAP + 8];
    __shared__ int n_tot_s;
    __shared__ float sacc[4][HH];
    __shared__ float sl[4];

    const float edj = ed2[j];
    const int n = min(cnt[j], CAP);

    // ---- stage 1: fill p/idx (102 edges < 256 threads = one round) ----
    for (int e = tid; e < n; e += 256) {
        int i = csc[j * CAP + e];
        idx_l[e] = (unsigned short)i;
        p_l[e] = lrelu_exp(es2[i] + edj);
    }
    if (tid == 0) {
        int m = n;
        if (!row_full[j]) {
            idx_l[m] = (unsigned short)j;
            p_l[m] = lrelu_exp(es2[j] + edj);
            ++m;
        }
        const int nf = *nfull;
        for (int f = 0; f < nf && m < CAP + 8; ++f) {
            int i = full_list[f];
            idx_l[m] = (unsigned short)i;
            p_l[m] = lrelu_exp(es2[i] + edj);
            ++m;
        }
        n_tot_s = m;
    }
    __syncthreads();

    // ---- stage 2: streaming accumulate (wave-uniform e, 256B row reads) --
    const int grp = tid >> 6;         // edge group 0..3 (one wave each)
    const int d = tid & 63;           // h-dim 0..63
    {
        const int m = n_tot_s;
        float acc = 0.0f, l = 0.0f;
        #pragma unroll 4
        for (int e = grp; e < m; e += 4) {
            float p = p_l[e];
            int i = idx_l[e];
            l += p;
            acc += p * h2g[i * HH + d];
        }
        sacc[grp][d] = acc;
        if (d == 0) sl[grp] = l;
    }
    __syncthreads();

    // ---- stage 3: combine + fc + leaky_relu ----
    if (grp == 0) {                    // tid 0..63 = one wave
        float a = sacc[0][d] + sacc[1][d] + sacc[2][d] + sacc[3][d];
        float L = sl[0] + sl[1] + sl[2] + sl[3];
        float v = a / L + gat2_b[d];
        float t = v * fc_W[d];
        #pragma unroll
        for (int off = 32; off >= 1; off >>= 1)
            t += __shfl_down(t, off, 64);
        if (d == 0) {
            float r = t + fc_b[0];
            out[j] = (r > 0.0f) ? r : 0.2f * r;
        }
    }
}

extern "C" void kernel_launch(void* const* d_in, const int* in_sizes, int n_in,
                              void* d_out, int out_size, void* d_ws, size_t ws_size,
                              hipStream_t stream)
{
    const float* inputs   = (const float*)d_in[0];
    // d_in[1] (relation), d_in[3] (rel_w_W), d_in[4] (rel_w_b) are dead:
    // softmax(rel_mask + weight) > 0 depends only on rel_mask.
    const float* rel_mask = (const float*)d_in[2];
    const float* w_ih0 = (const float*)d_in[5];
    const float* w_hh0 = (const float*)d_in[6];
    const float* b_ih0 = (const float*)d_in[7];
    const float* b_hh0 = (const float*)d_in[8];
    const float* w_ih1 = (const float*)d_in[9];
    const float* w_hh1 = (const float*)d_in[10];
    const float* b_ih1 = (const float*)d_in[11];
    const float* b_hh1 = (const float*)d_in[12];
    const float* gat1_W  = (const float*)d_in[13];
    const float* gat1_as = (const float*)d_in[14];
    const float* gat1_ad = (const float*)d_in[15];
    const float* gat1_b  = (const float*)d_in[16];
    const float* gat2_W  = (const float*)d_in[17];
    const float* gat2_as = (const float*)d_in[18];
    const float* gat2_ad = (const float*)d_in[19];
    const float* gat2_b  = (const float*)d_in[20];
    const float* fc_W = (const float*)d_in[21];
    const float* fc_b = (const float*)d_in[22];
    float* out = (float*)d_out;

    float* ws = (float*)d_ws;
    float* x_out = ws;                       // 2048*64 (unused since R13)
    float* h1g = x_out + NN * HH;            // 2048*16
    float* es1 = h1g + NN * GATH;            // 2048
    float* ed1 = es1 + NN;                   // 2048
    float* hrel = ed1 + NN;                  // 2048*16 (unused since R12)
    float* h2g = hrel + NN * GATH;           // 2048*64
    float* es2 = h2g + NN * HH;              // 2048
    float* ed2 = es2 + NN;                   // 2048
    int* cnt = (int*)(ed2 + NN);             // 2048
    int* row_full = cnt + NN;                // 2048
    int* full_list = row_full + NN;          // 2048
    int* nfull = full_list + NN;             // 1 (+pad)
    int* csc = nfull + 8;                    // 2048*CAP = 2 MB

    k_zero<<<(NN + 255) / 256, 256, 0, stream>>>(cnt, nfull);
    k_lstm_eh<<<NN / LNB, 256, 0, stream>>>(inputs, w_ih0, w_hh0, b_ih0, b_hh0,
                                            w_ih1, w_hh1, b_ih1, b_hh1,
                                            rel_mask, cnt, csc, row_full,
                                            full_list, nfull,
                                            gat1_W, gat1_as, gat1_ad,
                                            h1g, es1, ed1);
    k_gat1s2<<<NN / 4, 256, 0, stream>>>(cnt, csc, row_full, full_list, nfull,
                                         h1g, es1, ed1, gat1_b,
                                         gat2_W, gat2_as, gat2_ad,
                                         h2g, es2, ed2);
    k_gat2s<<<NN, 256, 0, stream>>>(cnt, csc, row_full, full_list, nfull,
                                    h2g, es2, ed2, gat2_b, fc_W, fc_b, out);
}

// Round 10
// 429.982 us; speedup vs baseline: 6.4595x; 1.0483x over previous
//
#include <hip/hip_runtime.h>
#include <math.h>

#define NN 2048
#define TT 32
#define FIN 5
#define HH 64
#define G4 256     // 4*H
#define GATH 16
#define CAP 256    // max CSC edges/column: mean 102, sigma ~10 -> +15 sigma safe

// ---------- helpers ----------
__device__ __forceinline__ float sigf(float x) {
    return 1.0f / (1.0f + __expf(-x));
}
__device__ __forceinline__ float tanh_fast(float x) {
    x = fminf(fmaxf(x, -15.0f), 15.0f);
    float t = __expf(2.0f * x);
    return (t - 1.0f) / (t + 1.0f);
}
__device__ __forceinline__ float dot4(float4 a, float4 b) {
    return a.x * b.x + a.y * b.y + a.z * b.z + a.w * b.w;
}
__device__ __forceinline__ float lrelu_exp(float x) {
    x = (x > 0.0f) ? x : 0.2f * x;
    return __expf(x);
}

// ---------- fused: atomic-free edge build + 2-layer LSTM + h1 epilogue ----
// R17: R14's prologue cost 48us (251 vs R7's 203) = device-atomic contention
// (~418K atomicAdds on the 8KB cnt array in the first ~10us of the grid).
// Fix: column ownership. Block b owns CSC columns 2b,2b+1: scans the mask
// column-wise (float2 per row; scattered wave-loads, L3 absorbs the 8x line
// sharing), appends edge rows via LDS atomics (block-local, ~102 ops), and
// plain-stores csc/cnt as the SINGLE writer -> no device atomics, no k_zero.
// row_full from the coalesced row-scan (no csc side-effects); full_list/nfull
// deleted (GAT kernels scan row_full[] with a block-any skip; P(full row)
// ~ e^-105 so the path is never taken, but stays correct).
// LSTM body + h1 epilogue = R14 verbatim (absmax 0.0 measured).
#define LNB 2
__global__ __launch_bounds__(256, 1)
void k_lstm_eh(
    const float* __restrict__ inputs,
    const float* __restrict__ w_ih0, const float* __restrict__ w_hh0,
    const float* __restrict__ b_ih0, const float* __restrict__ b_hh0,
    const float* __restrict__ w_ih1, const float* __restrict__ w_hh1,
    const float* __restrict__ b_ih1, const float* __restrict__ b_hh1,
    const float* __restrict__ rel_mask,
    int* __restrict__ cnt, int* __restrict__ csc,
    int* __restrict__ row_full,
    const float* __restrict__ gat1_W,
    const float* __restrict__ gat1_as, const float* __restrict__ gat1_ad,
    float* __restrict__ h1g, float* __restrict__ es1, float* __restrict__ ed1)
{
    __shared__ float x_lds[LNB * TT * FIN];        // 320 f
    __shared__ float hist[LNB][TT + 1][HH];        // 4224 f = 16.9 KB
    __shared__ float g_lds[LNB * G4];              // 512 f
    __shared__ float h1_lds[LNB * HH];             // 128 f
    __shared__ float Wl[HH * GATH];                // 1024 f (gat1_W staged)
    __shared__ float h1l[LNB][GATH];
    __shared__ int csc_l[LNB][CAP];                // 2 KB: block-local CSC
    __shared__ int ccnt[LNB];
    __shared__ int s_any[LNB];

    const int tid = threadIdx.x;
    const int n0 = blockIdx.x * LNB;
    const int g = tid;                 // gate row 0..255
    const int cnb = tid >> 6;          // combine: node (tid<128): 0..1
    const int ck = tid & 63;           // combine: cell 0..63

    for (int idx = tid; idx < LNB * TT * FIN; idx += 256)
        x_lds[idx] = inputs[n0 * (TT * FIN) + idx];
    for (int idx = tid; idx < HH * GATH; idx += 256)
        Wl[idx] = gat1_W[idx];
    if (tid < LNB * HH) {
        hist[tid >> 6][0][tid & 63] = 0.0f;
        h1_lds[tid] = 0.0f;
    }
    if (tid < LNB) { s_any[tid] = 0; ccnt[tid] = 0; }
    __syncthreads();

    // ---- column scan: build CSC cols n0, n0+1 (LDS atomics only) ----
    for (int r = tid; r < NN; r += 256) {
        float2 v = *(const float2*)(rel_mask + r * NN + n0);
        if (v.x == 0.0f && r != n0) {
            int s = atomicAdd(&ccnt[0], 1);
            if (s < CAP) csc_l[0][s] = r;
        }
        if (v.y == 0.0f && r != n0 + 1) {
            int s = atomicAdd(&ccnt[1], 1);
            if (s < CAP) csc_l[1][s] = r;
        }
    }
    // ---- row scan: row_full for rows n0, n0+1 (coalesced, no side effects)
    {
        bool m0 = false, m1 = false;
        for (int j = tid; j < NN; j += 256) {
            m0 |= (rel_mask[(n0 + 0) * NN + j] == 0.0f);
            m1 |= (rel_mask[(n0 + 1) * NN + j] == 0.0f);
        }
        if (m0) atomicOr(&s_any[0], 1);
        if (m1) atomicOr(&s_any[1], 1);
    }
    __syncthreads();
    // ---- single-writer global stores: no device atomics anywhere ----
    {
        const int c0 = min(ccnt[0], CAP), c1 = min(ccnt[1], CAP);
        for (int e = tid; e < c0; e += 256) csc[n0 * CAP + e] = csc_l[0][e];
        for (int e = tid; e < c1; e += 256) csc[(n0 + 1) * CAP + e] = csc_l[1][e];
        if (tid == 0) { cnt[n0] = c0; cnt[n0 + 1] = c1; }
        if (tid < LNB) row_full[n0 + tid] = s_any[tid] ? 0 : 1;
    }

    // ================= Phase A: layer 0 (R7 verbatim) =================
    {
        float4 w0[16];
        {
            const float4* p = (const float4*)(w_hh0 + g * HH);
            #pragma unroll
            for (int k = 0; k < 16; ++k) w0[k] = p[k];
        }
        float xw0 = w_ih0[g * FIN + 0];
        float xw1 = w_ih0[g * FIN + 1];
        float xw2 = w_ih0[g * FIN + 2];
        float xw3 = w_ih0[g * FIN + 3];
        float xw4 = w_ih0[g * FIN + 4];
        const float bias0 = b_ih0[g] + b_hh0[g];
        float cA = 0.0f;

        __syncthreads();

        for (int t = 1; t <= TT; ++t) {
            #pragma unroll
            for (int nb = 0; nb < LNB; ++nb) {
                const float4* hv = (const float4*)&hist[nb][t - 1][0];
                float s0 = 0.f, s1 = 0.f, s2 = 0.f, s3 = 0.f;
                #pragma unroll
                for (int k = 0; k < 4; ++k) {
                    s0 += dot4(w0[k],      hv[k]);
                    s1 += dot4(w0[4 + k],  hv[4 + k]);
                    s2 += dot4(w0[8 + k],  hv[8 + k]);
                    s3 += dot4(w0[12 + k], hv[12 + k]);
                }
                const float* xv = &x_lds[nb * (TT * FIN) + (t - 1) * FIN];
                float a = bias0 + xw0 * xv[0] + xw1 * xv[1] + xw2 * xv[2] +
                          xw3 * xv[3] + xw4 * xv[4];
                g_lds[nb * G4 + g] = a + (s0 + s1) + (s2 + s3);
            }
            __syncthreads();
            if (tid < LNB * HH) {
                const int base = cnb * G4 + ck;
                float gi = g_lds[base];
                float gf = g_lds[base + 64];
                float gg = g_lds[base + 128];
                float go = g_lds[base + 192];
                cA = sigf(gf) * cA + sigf(gi) * tanh_fast(gg);
                hist[cnb][t][ck] = sigf(go) * tanh_fast(cA);
            }
            __syncthreads();
        }
    }

    // ================= Phase B: layer 1 (R7 verbatim) =================
    {
        float4 wi[16], wh[16];
        {
            const float4* pi = (const float4*)(w_ih1 + g * HH);
            const float4* ph = (const float4*)(w_hh1 + g * HH);
            #pragma unroll
            for (int k = 0; k < 16; ++k) { wi[k] = pi[k]; wh[k] = ph[k]; }
        }
        const float bias1 = b_ih1[g] + b_hh1[g];
        float cA = 0.0f;

        for (int t = 1; t <= TT; ++t) {
            #pragma unroll
            for (int nb = 0; nb < LNB; ++nb) {
                const float4* xv = (const float4*)&hist[nb][t][0];
                const float4* hv = (const float4*)&h1_lds[nb * HH];
                float s0 = 0.f, s1 = 0.f, s2 = 0.f, s3 = 0.f;
                float u0 = 0.f, u1 = 0.f, u2 = 0.f, u3 = 0.f;
                #pragma unroll
                for (int k = 0; k < 4; ++k) {
                    s0 += dot4(wi[k],      xv[k]);
                    s1 += dot4(wi[4 + k],  xv[4 + k]);
                    s2 += dot4(wi[8 + k],  xv[8 + k]);
                    s3 += dot4(wi[12 + k], xv[12 + k]);
                    u0 += dot4(wh[k],      hv[k]);
                    u1 += dot4(wh[4 + k],  hv[4 + k]);
                    u2 += dot4(wh[8 + k],  hv[8 + k]);
                    u3 += dot4(wh[12 + k], hv[12 + k]);
                }
                g_lds[nb * G4 + g] =
                    bias1 + ((s0 + s1) + (s2 + s3)) + ((u0 + u1) + (u2 + u3));
            }
            __syncthreads();
            if (tid < LNB * HH) {
                const int base = cnb * G4 + ck;
                float gi = g_lds[base];
                float gf = g_lds[base + 64];
                float gg = g_lds[base + 128];
                float go = g_lds[base + 192];
                cA = sigf(gf) * cA + sigf(gi) * tanh_fast(gg);
                h1_lds[cnb * HH + ck] = sigf(go) * tanh_fast(cA);
            }
            __syncthreads();
        }
    }

    // ---- epilogue: h1 = x @ gat1_W ; es1/ed1 (x never leaves LDS) ----
    if (tid < LNB * GATH) {            // 32 threads, 64-len dots
        const int ln = tid >> 4, dd = tid & 15;
        float acc = 0.0f;
        #pragma unroll 16
        for (int k = 0; k < HH; ++k)
            acc += h1_lds[ln * HH + k] * Wl[k * GATH + dd];
        h1g[(n0 + ln) * GATH + dd] = acc;
        h1l[ln][dd] = acc;
    }
    __syncthreads();
    if (tid < LNB) {
        float e_s = 0.0f, e_d = 0.0f;
        #pragma unroll
        for (int t = 0; t < GATH; ++t) {
            float hv = h1l[tid][t];
            e_s += hv * gat1_as[t];
            e_d += hv * gat1_ad[t];
        }
        es1[n0 + tid] = e_s;
        ed1[n0 + tid] = e_d;
    }
}

// ---------- GAT1 + h2 + es2/ed2 (R15 structure, full_list -> row_full scan)
__global__ __launch_bounds__(256) void k_gat1s2(
    const int* __restrict__ cnt, const int* __restrict__ csc,
    const int* __restrict__ row_full,
    const float* __restrict__ h1g, const float* __restrict__ es1,
    const float* __restrict__ ed1, const float* __restrict__ gat1_b,
    const float* __restrict__ W2,
    const float* __restrict__ a_s2, const float* __restrict__ a_d2,
    float* __restrict__ h2g, float* __restrict__ es2, float* __restrict__ ed2)
{
    const int tid = threadIdx.x;
    const int jb = blockIdx.x * 4;

    __shared__ float p_l[4][CAP + 8];
    __shared__ unsigned short idx_l[4][CAP + 8];
    __shared__ int n_tot[4];
    __shared__ int s_anyfull;
    __shared__ float sacc[4][4][GATH];
    __shared__ float sl[4][4];
    __shared__ float hl[4][GATH];     // hrel rows (LDS only, never global)
    __shared__ float h2l[4][HH];

    if (tid == 0) s_anyfull = 0;
    __syncthreads();

    // ---- stage 1: fill p/idx (all edges in parallel, coalesced csc) ----
    #pragma unroll
    for (int c = 0; c < 4; ++c) {
        const int j = jb + c;
        const float edj = ed1[j];
        const int n = min(cnt[j], CAP);
        for (int e = tid; e < n; e += 256) {
            int i = csc[j * CAP + e];
            idx_l[c][e] = (unsigned short)i;
            p_l[c][e] = lrelu_exp(es1[i] + edj);
        }
    }
    // block-any full-row check (coalesced 8KB scan; essentially always 0)
    {
        int any = 0;
        for (int r = tid; r < NN; r += 256) any |= row_full[r];
        if (any) atomicOr(&s_anyfull, 1);
    }
    __syncthreads();
    if (tid < 4) {                     // append self (+ full rows, never)
        const int c = tid, j = jb + c;
        const float edj = ed1[j];
        int m = min(cnt[j], CAP);
        if (!row_full[j]) {
            idx_l[c][m] = (unsigned short)j;
            p_l[c][m] = lrelu_exp(es1[j] + edj);
            ++m;
        }
        if (s_anyfull) {
            for (int f = 0; f < NN && m < CAP + 8; ++f) {
                if (row_full[f]) {
                    idx_l[c][m] = (unsigned short)f;
                    p_l[c][m] = lrelu_exp(es1[f] + edj);
                    ++m;
                }
            }
        }
        n_tot[c] = m;
    }
    __syncthreads();

    // ---- stage 2: streaming accumulate ----
    const int lc = tid >> 6;          // col in block 0..3
    const int grp = (tid >> 4) & 3;   // edge group 0..3
    const int d = tid & 15;           // h-dim 0..15
    {
        const int m = n_tot[lc];
        float acc = 0.0f, l = 0.0f;
        #pragma unroll 4
        for (int e = grp; e < m; e += 4) {
            float p = p_l[lc][e];
            int i = idx_l[lc][e];
            l += p;
            acc += p * h1g[i * GATH + d];
        }
        sacc[lc][grp][d] = acc;
        if (d == 0) sl[lc][grp] = l;
    }
    __syncthreads();

    // ---- stage 3: combine -> hrel (LDS only) ----
    if (grp == 0) {
        float a = sacc[lc][0][d] + sacc[lc][1][d] + sacc[lc][2][d] + sacc[lc][3][d];
        float L = sl[lc][0] + sl[lc][1] + sl[lc][2] + sl[lc][3];
        hl[lc][d] = fmaxf(a / L + gat1_b[d], 0.0f);
    }
    __syncthreads();

    // ---- h2 matvec: thread (lc2, jj) computes h2[j2][jj] ----
    {
        const int lc2 = tid >> 6;
        const int jj = tid & 63;
        float acc2 = 0.0f;
        #pragma unroll
        for (int k = 0; k < GATH; ++k)
            acc2 += hl[lc2][k] * W2[k * HH + jj];   // W2 coalesced, L2-hot
        const int j2 = jb + lc2;
        h2g[j2 * HH + jj] = acc2;
        h2l[lc2][jj] = acc2;
    }
    __syncthreads();
    if (tid < 4) {
        float e_s = 0.0f, e_d = 0.0f;
        #pragma unroll 16
        for (int t = 0; t < HH; ++t) {
            float hv = h2l[tid][t];
            e_s += hv * a_s2[t];
            e_d += hv * a_d2[t];
        }
        es2[jb + tid] = e_s;
        ed2[jb + tid] = e_d;
    }
}

// ---------- GAT2 + fc + leaky_relu (R15 structure, full_list -> row_full) --
__global__ __launch_bounds__(256) void k_gat2s(
    const int* __restrict__ cnt, const int* __restrict__ csc,
    const int* __restrict__ row_full,
    const float* __restrict__ h2g, const float* __restrict__ es2,
    const float* __restrict__ ed2, const float* __restrict__ gat2_b,
    const float* __restrict__ fc_W, const float* __restrict__ fc_b,
    float* __restrict__ out)
{
    const int tid = threadIdx.x;
    const int j = blockIdx.x;

    __shared__ float p_l[CAP + 8];
    __shared__ unsigned short idx_l[CAP + 8];
    __shared__ int n_tot_s;
    __shared__ int s_anyfull;
    __shared__ float sacc[4][HH];
    __shared__ float sl[4];

    if (tid == 0) s_anyfull = 0;
    __syncthreads();

    const float edj = ed2[j];
    const int n = min(cnt[j], CAP);

    // ---- stage 1: fill p/idx (102 edges < 256 threads = one round) ----
    for (int e = tid; e < n; e += 256) {
        int i = csc[j * CAP + e];
        idx_l[e] = (unsigned short)i;
        p_l[e] = lrelu_exp(es2[i] + edj);
    }
    {
        int any = 0;
        for (int r = tid; r < NN; r += 256) any |= row_full[r];
        if (any) atomicOr(&s_anyfull, 1);
    }
    __syncthreads();
    if (tid == 0) {
        int m = n;
        if (!row_full[j]) {
            idx_l[m] = (unsigned short)j;
            p_l[m] = lrelu_exp(es2[j] + edj);
            ++m;
        }
        if (s_anyfull) {
            for (int f = 0; f < NN && m < CAP + 8; ++f) {
                if (row_full[f]) {
                    idx_l[m] = (unsigned short)f;
                    p_l[m] = lrelu_exp(es2[f] + edj);
                    ++m;
                }
            }
        }
        n_tot_s = m;
    }
    __syncthreads();

    // ---- stage 2: streaming accumulate (wave-uniform e, 256B row reads) --
    const int grp = tid >> 6;         // edge group 0..3 (one wave each)
    const int d = tid & 63;           // h-dim 0..63
    {
        const int m = n_tot_s;
        float acc = 0.0f, l = 0.0f;
        #pragma unroll 4
        for (int e = grp; e < m; e += 4) {
            float p = p_l[e];
            int i = idx_l[e];
            l += p;
            acc += p * h2g[i * HH + d];
        }
        sacc[grp][d] = acc;
        if (d == 0) sl[grp] = l;
    }
    __syncthreads();

    // ---- stage 3: combine + fc + leaky_relu ----
    if (grp == 0) {                    // tid 0..63 = one wave
        float a = sacc[0][d] + sacc[1][d] + sacc[2][d] + sacc[3][d];
        float L = sl[0] + sl[1] + sl[2] + sl[3];
        float v = a / L + gat2_b[d];
        float t = v * fc_W[d];
        #pragma unroll
        for (int off = 32; off >= 1; off >>= 1)
            t += __shfl_down(t, off, 64);
        if (d == 0) {
            float r = t + fc_b[0];
            out[j] = (r > 0.0f) ? r : 0.2f * r;
        }
    }
}

extern "C" void kernel_launch(void* const* d_in, const int* in_sizes, int n_in,
                              void* d_out, int out_size, void* d_ws, size_t ws_size,
                              hipStream_t stream)
{
    const float* inputs   = (const float*)d_in[0];
    // d_in[1] (relation), d_in[3] (rel_w_W), d_in[4] (rel_w_b) are dead:
    // softmax(rel_mask + weight) > 0 depends only on rel_mask.
    const float* rel_mask = (const float*)d_in[2];
    const float* w_ih0 = (const float*)d_in[5];
    const float* w_hh0 = (const float*)d_in[6];
    const float* b_ih0 = (const float*)d_in[7];
    const float* b_hh0 = (const float*)d_in[8];
    const float* w_ih1 = (const float*)d_in[9];
    const float* w_hh1 = (const float*)d_in[10];
    const float* b_ih1 = (const float*)d_in[11];
    const float* b_hh1 = (const float*)d_in[12];
    const float* gat1_W  = (const float*)d_in[13];
    const float* gat1_as = (const float*)d_in[14];
    const float* gat1_ad = (const float*)d_in[15];
    const float* gat1_b  = (const float*)d_in[16];
    const float* gat2_W  = (const float*)d_in[17];
    const float* gat2_as = (const float*)d_in[18];
    const float* gat2_ad = (const float*)d_in[19];
    const float* gat2_b  = (const float*)d_in[20];
    const float* fc_W = (const float*)d_in[21];
    const float* fc_b = (const float*)d_in[22];
    float* out = (float*)d_out;

    float* ws = (float*)d_ws;
    float* x_out = ws;                       // 2048*64 (unused since R13)
    float* h1g = x_out + NN * HH;            // 2048*16
    float* es1 = h1g + NN * GATH;            // 2048
    float* ed1 = es1 + NN;                   // 2048
    float* hrel = ed1 + NN;                  // 2048*16 (unused since R12)
    float* h2g = hrel + NN * GATH;           // 2048*64
    float* es2 = h2g + NN * HH;              // 2048
    float* ed2 = es2 + NN;                   // 2048
    int* cnt = (int*)(ed2 + NN);             // 2048
    int* row_full = cnt + NN;                // 2048
    int* full_list = row_full + NN;          // 2048 (unused since R17)
    int* nfull = full_list + NN;             // (unused since R17)
    int* csc = nfull + 8;                    // 2048*CAP = 2 MB

    k_lstm_eh<<<NN / LNB, 256, 0, stream>>>(inputs, w_ih0, w_hh0, b_ih0, b_hh0,
                                            w_ih1, w_hh1, b_ih1, b_hh1,
                                            rel_mask, cnt, csc, row_full,
                                            gat1_W, gat1_as, gat1_ad,
                                            h1g, es1, ed1);
    k_gat1s2<<<NN / 4, 256, 0, stream>>>(cnt, csc, row_full,
                                         h1g, es1, ed1, gat1_b,
                                         gat2_W, gat2_as, gat2_ad,
                                         h2g, es2, ed2);
    k_gat2s<<<NN, 256, 0, stream>>>(cnt, csc, row_full,
                                    h2g, es2, ed2, gat2_b, fc_W, fc_b, out);
}